// Round 9
// baseline (696.848 us; speedup 1.0000x reference)
//
#include <hip/hip_runtime.h>
#include <math.h>

// ---------------------------------------------------------------------------
// Decoder_82764019794508: LIIF-style decoder.
// R9: atomic-free counting sort. R8's sort_scatter (295k global atomicAdds
// over 288 cursors) serialized at 172 us, VALUBusy 0.2%. Replace with the
// deterministic two-pass sort: per-block LDS hist + local rank (u8) ->
// bucket-major scan of block counts -> rank-based scatter. No global atomics.
// Decoder / conv pipeline byte-identical to R8.
// ---------------------------------------------------------------------------

#define HQ 384
#define HA 192
#define NQ (2 * HQ * HQ)   // 294912 queries
#define NB (NQ / 256)      // 1152 sort blocks
#define NBKT 288           // 2 batches x 12x12 tiles of 16x16 px

typedef _Float16 half8  __attribute__((ext_vector_type(8)));
typedef _Float16 half4v __attribute__((ext_vector_type(4)));
typedef float    float4v __attribute__((ext_vector_type(4)));

// bucket id from query coords: corner k=0 (vy=vx=-1) pixel, 16x16 tiles
__device__ __forceinline__ int bucket_id(int q, float cy, float cx) {
    const float LO = -1.0f + 1e-7f, HI = 1.0f - 1e-7f;
    const float RXY = 1.0f / (float)HA;
    float c0 = fminf(fmaxf((cy - RXY) + 1e-7f, LO), HI);
    float c1 = fminf(fmaxf((cx - RXY) + 1e-7f, LO), HI);
    int iy = (int)rintf(((c0 + 1.f) * (float)HA) * 0.5f - 0.5f);
    int ix = (int)rintf(((c1 + 1.f) * (float)HA) * 0.5f - 0.5f);
    iy = min(max(iy, 0), HA - 1);
    ix = min(max(ix, 0), HA - 1);
    int b = q / (HQ * HQ);
    return b * 144 + (iy >> 4) * 12 + (ix >> 4);
}

// ---- K0: pack ALL weights into per-lane MFMA B-fragments ------------------
__global__ void prep_all(const float* __restrict__ mw0,
                         const float* __restrict__ mw1,
                         const float* __restrict__ wf,
                         _Float16* __restrict__ fragTab,
                         _Float16* __restrict__ fragTabW) {
    int t = blockIdx.x * 256 + threadIdx.x;
    if (t < 1536) {
        int f = t >> 6, L = t & 63;
        int n_ = L & 15, qd = L >> 4;
        _Float16 vals[8];
        if (f < 16) {
            int kc = f >> 2, nt = f & 3;
#pragma unroll
            for (int j = 0; j < 8; ++j) {
                int kk = kc * 32 + qd * 8 + j;
                vals[j] = (_Float16)((kk < 102) ? mw0[kk * 64 + nt * 16 + n_] : 0.f);
            }
        } else {
            int g = f - 16;
            int kc = g >> 2, nt = g & 3;
#pragma unroll
            for (int j = 0; j < 8; ++j) {
                int kk = kc * 32 + qd * 8 + j;
                vals[j] = (_Float16)mw1[kk * 64 + nt * 16 + n_];
            }
        }
#pragma unroll
        for (int j = 0; j < 8; ++j) fragTab[t * 8 + j] = vals[j];
    } else {
        int tw = t - 1536;
        if (tw >= 27 * 6 * 64) return;
        int s   = tw / 384;
        int rem = tw - s * 384;
        int nt  = rem >> 6;
        int L   = rem & 63;
        int n_  = L & 15, qd = L >> 4;
        int tap = s / 3, kc = s - tap * 3;
#pragma unroll
        for (int j = 0; j < 8; ++j) {
            int kch = kc * 32 + qd * 8 + j;
            fragTabW[tw * 8 + j] = (_Float16)wf[(tap * 96 + kch) * 96 + nt * 16 + n_];
        }
    }
}

// ---- K_s1: per-block LDS histogram + local rank (no global atomics) -------
__global__ void sort_count(const float* __restrict__ coords,
                           int* __restrict__ blockCnt,
                           unsigned char* __restrict__ lrank) {
    __shared__ int lh[NBKT];
    const int tid = threadIdx.x;
    for (int i = tid; i < NBKT; i += 256) lh[i] = 0;
    __syncthreads();
    const int q = blockIdx.x * 256 + tid;
    float cy = coords[(size_t)q * 2 + 0];
    float cx = coords[(size_t)q * 2 + 1];
    int r = atomicAdd(&lh[bucket_id(q, cy, cx)], 1);   // LDS atomic only
    lrank[q] = (unsigned char)r;
    __syncthreads();
    for (int i = tid; i < NBKT; i += 256)
        blockCnt[blockIdx.x * NBKT + i] = lh[i];       // coalesced store
}

// ---- K_s2: exclusive scan of blockCnt in bucket-major order ---------------
// one block, 1024 threads; total = NBKT*NB = 331776 = 1024 * 324
__global__ void sort_scan(const int* __restrict__ blockCnt,
                          int* __restrict__ blockOff) {
    __shared__ int s[1024];
    const int t = threadIdx.x;
    const int chunk = (NBKT * NB) / 1024;   // 324
    const int base = t * chunk;

    int sum = 0;
    for (int i = 0; i < chunk; ++i) {
        int li = base + i;
        int bkt = li / NB, blk = li - bkt * NB;
        sum += blockCnt[blk * NBKT + bkt];
    }
    s[t] = sum;
    __syncthreads();
    for (int off = 1; off < 1024; off <<= 1) {
        int x = (t >= off) ? s[t - off] : 0;
        __syncthreads();
        s[t] += x;
        __syncthreads();
    }
    int run = s[t] - sum;   // exclusive prefix of this thread's chunk
    for (int i = 0; i < chunk; ++i) {
        int li = base + i;
        int bkt = li / NB, blk = li - bkt * NB;
        int c = blockCnt[blk * NBKT + bkt];
        blockOff[blk * NBKT + bkt] = run;
        run += c;
    }
}

// ---- K_s3: scatter query indices + packed per-query data (no atomics) -----
__global__ void sort_scatter(const float* __restrict__ coords,
                             const float* __restrict__ cells,
                             const int* __restrict__ blockOff,
                             const unsigned char* __restrict__ lrank,
                             int* __restrict__ qidx,
                             float4v* __restrict__ qdata) {
    const int q = blockIdx.x * 256 + threadIdx.x;
    float cy = coords[(size_t)q * 2 + 0];
    float cx = coords[(size_t)q * 2 + 1];
    int bkt = bucket_id(q, cy, cx);
    int pos = blockOff[blockIdx.x * NBKT + bkt] + (int)lrank[q];
    qidx[pos] = q;
    float4v d = {cy, cx,
                 cells[(size_t)q * 2 + 0] * (float)HA,
                 cells[(size_t)q * 2 + 1] * (float)HA};
    qdata[pos] = d;
}

// ---- K1: fused 1x1 convs for a4s (96->32) and a32s (160->32), fp32 out ----
__global__ void conv1x1_ab(const float* __restrict__ feats4,
                           const float* __restrict__ w4,
                           const float* __restrict__ b4,
                           const float* __restrict__ feats32,
                           const float* __restrict__ w32,
                           const float* __restrict__ b32,
                           float* __restrict__ a4s,
                           float* __restrict__ a32s) {
    int blk = blockIdx.x;
    if (blk < 2304) {
        int t = blk * 256 + threadIdx.x;
        int p = t >> 5, c = t & 31;
        const float* xr = feats4 + (size_t)p * 96;
        float acc = b4[c];
#pragma unroll
        for (int i = 0; i < 96; ++i) acc = fmaf(xr[i], w4[i * 32 + c], acc);
        a4s[(size_t)p * 32 + c] = fmaxf(acc, 0.f);
    } else {
        int t = (blk - 2304) * 256 + threadIdx.x;
        int p = t >> 5, c = t & 31;
        const float* xr = feats32 + (size_t)p * 160;
        float acc = b32[c];
#pragma unroll
        for (int i = 0; i < 160; ++i) acc = fmaf(xr[i], w32[i * 32 + c], acc);
        a32s[(size_t)p * 32 + c] = fmaxf(acc, 0.f);
    }
}

// ---- K2: build xcat (fp16), 3 slices selected by blockIdx.y ---------------
__global__ void build_xcat(const float* __restrict__ feats2,
                           const float* __restrict__ w2,
                           const float* __restrict__ b2,
                           const float* __restrict__ a4s,
                           const float* __restrict__ a32s,
                           _Float16* __restrict__ xcatH) {
    const int z = blockIdx.y;
    int t = blockIdx.x * 256 + threadIdx.x;
    int c = t & 31;
    int p = t >> 5;

    if (z == 0) {
        const float* xr = feats2 + (size_t)p * 64;
        float acc = b2[c];
#pragma unroll
        for (int i = 0; i < 64; ++i) acc = fmaf(xr[i], w2[i * 32 + c], acc);
        xcatH[(size_t)p * 96 + c] = (_Float16)fmaxf(acc, 0.f);
        return;
    }

    const float* src = (z == 1) ? a4s : a32s;
    const int   S    = (z == 1) ? 96 : 24;
    const float inv  = (z == 1) ? 0.5f : 0.125f;
    const int   coff = (z == 1) ? 32 : 64;

    int x = p % HA;
    int r = p / HA;
    int y = r % HA;
    int b = r / HA;

    float u = ((float)y + 0.5f) * inv - 0.5f;
    float v = ((float)x + 0.5f) * inv - 0.5f;
    float fu = floorf(u), fv = floorf(v);
    float wu = u - fu, wv = v - fv;
    int y0 = (int)fu, x0 = (int)fv;
    int y1 = min(y0 + 1, S - 1);
    int x1 = min(x0 + 1, S - 1);
    y0 = max(y0, 0);
    x0 = max(x0, 0);

    const float* sb = src + (size_t)b * S * S * 32 + c;
    float v00 = sb[(y0 * S + x0) * 32];
    float v01 = sb[(y0 * S + x1) * 32];
    float v10 = sb[(y1 * S + x0) * 32];
    float v11 = sb[(y1 * S + x1) * 32];
    float t0 = v00 * (1.f - wu) + v10 * wu;
    float t1 = v01 * (1.f - wu) + v11 * wu;
    float o  = t0 * (1.f - wv) + t1 * wv;
    xcatH[(size_t)p * 96 + coff + c] = (_Float16)o;
}

// ---- K3: 3x3 conv 96->96 + bias + ReLU via fp16 MFMA, fp16 in/out ---------
__launch_bounds__(256, 4)
__global__ void conv3x3_mfma(const _Float16* __restrict__ xH,
                             const _Float16* __restrict__ fragTabW,
                             const float* __restrict__ bias,
                             _Float16* __restrict__ yH) {
    __shared__ _Float16 lds[10 * 18 * 104];
    const int tid = threadIdx.x;
    const int lane = tid & 63;
    const int wv   = tid >> 6;
    const int n_   = lane & 15;
    const int qd   = lane >> 4;
    const int nh   = wv & 1;
    const int yg   = wv >> 1;
    const int bx0  = blockIdx.x * 16;
    const int by0  = blockIdx.y * 8;
    const int b    = blockIdx.z;

    for (int idx = tid; idx < 2160; idx += 256) {
        int hy  = idx / 216;
        int rem = idx - hy * 216;
        int hx  = rem / 12;
        int cc  = rem - hx * 12;
        int gy = by0 + hy - 1, gx = bx0 + hx - 1;
        half8 v = {(_Float16)0.f, (_Float16)0.f, (_Float16)0.f, (_Float16)0.f,
                   (_Float16)0.f, (_Float16)0.f, (_Float16)0.f, (_Float16)0.f};
        if (gy >= 0 && gy < HA && gx >= 0 && gx < HA)
            v = *(const half8*)(xH + (((size_t)b * HA + gy) * HA + gx) * 96 + cc * 8);
        *(half8*)&lds[(hy * 18 + hx) * 104 + cc * 8] = v;
    }

    float bv[3];
#pragma unroll
    for (int j = 0; j < 3; ++j) bv[j] = bias[(nh * 3 + j) * 16 + n_];

    __syncthreads();

    float4v acc[4][3];
#pragma unroll
    for (int r = 0; r < 4; ++r)
#pragma unroll
        for (int j = 0; j < 3; ++j) {
            float4v z = {0.f, 0.f, 0.f, 0.f};
            acc[r][j] = z;
        }

#pragma unroll 1
    for (int ky = 0; ky < 3; ++ky)
#pragma unroll 1
        for (int kx = 0; kx < 3; ++kx) {
            const int tap = ky * 3 + kx;
#pragma unroll
            for (int kc = 0; kc < 3; ++kc) {
                const int s = tap * 3 + kc;
                half8 bf[3];
#pragma unroll
                for (int j = 0; j < 3; ++j)
                    bf[j] = *(const half8*)(fragTabW +
                            ((size_t)(s * 6 + nh * 3 + j) * 64 + lane) * 8);
#pragma unroll
                for (int r = 0; r < 4; ++r) {
                    const int yr = yg * 4 + r;
                    half8 a = *(const half8*)&lds[((yr + ky) * 18 + (n_ + kx)) * 104
                                                  + kc * 32 + qd * 8];
#pragma unroll
                    for (int j = 0; j < 3; ++j)
                        acc[r][j] = __builtin_amdgcn_mfma_f32_16x16x32_f16(
                            a, bf[j], acc[r][j], 0, 0, 0);
                }
            }
        }

#pragma unroll
    for (int r = 0; r < 4; ++r) {
        const int gy = by0 + yg * 4 + r;
#pragma unroll
        for (int j = 0; j < 3; ++j) {
            const int ch = (nh * 3 + j) * 16 + n_;
#pragma unroll
            for (int reg = 0; reg < 4; ++reg) {
                const int gx = bx0 + qd * 4 + reg;
                yH[(((size_t)b * HA + gy) * HA + gx) * 96 + ch] =
                    (_Float16)fmaxf(acc[r][j][reg] + bv[j], 0.f);
            }
        }
    }
}

// ---- K4: sorted 4-corner gather + MLP ensemble via fp16 MFMA --------------
__launch_bounds__(256, 3)
__global__ void decoder_mlp_mfma(const _Float16* __restrict__ asppH,
                                 const int* __restrict__ qidx,
                                 const float4v* __restrict__ qdata,
                                 const _Float16* __restrict__ fragTab,
                                 const float* __restrict__ mb0,
                                 const float* __restrict__ mb1,
                                 const float* __restrict__ mw2,
                                 const float* __restrict__ mb2,
                                 float* __restrict__ out) {
    __shared__ __align__(16) unsigned char smem[50688];
    _Float16* A   = (_Float16*)smem;              // 32768 B
    _Float16* Hb  = (_Float16*)(smem + 32768);    // 16384 B
    int*      pixL  = (int*)(smem + 49152);       // 512 B
    float*    areaL = (float*)(smem + 49664);     // 512 B
    float*    predL = (float*)(smem + 50176);     // 512 B

    const int tid  = threadIdx.x;
    const int lane = tid & 63;
    const int wv   = tid >> 6;
    const int n_   = lane & 15;
    const int qd   = lane >> 4;
    const int r    = (blockIdx.x & 7) * 1152 + (blockIdx.x >> 3);

    if (tid < 128) {
        const int lq = tid >> 2, k = tid & 3;
        const int sp = r * 32 + lq;
        const float4v d = qdata[sp];
        const int qq = qidx[sp];
        const int b  = qq / (HQ * HQ);
        const float cy = d[0], cx = d[1];
        const float rcy = d[2], rcx = d[3];

        const float LO = -1.0f + 1e-7f, HI = 1.0f - 1e-7f;
        const float RXY = 1.0f / (float)HA;
        const float vy = (k < 2) ? -1.f : 1.f;
        const float vx = (k & 1) ? 1.f : -1.f;

        float c0 = fminf(fmaxf((cy + vy * RXY) + 1e-7f, LO), HI);
        float c1 = fminf(fmaxf((cx + vx * RXY) + 1e-7f, LO), HI);
        int iy = (int)rintf(((c0 + 1.f) * (float)HA) * 0.5f - 0.5f);
        int ix = (int)rintf(((c1 + 1.f) * (float)HA) * 0.5f - 0.5f);
        iy = min(max(iy, 0), HA - 1);
        ix = min(max(ix, 0), HA - 1);

        const float cs0 = (((float)iy + 0.5f) / (float)HA) * 2.f - 1.f;
        const float cs1 = (((float)ix + 0.5f) / (float)HA) * 2.f - 1.f;
        const float r0 = (cy - cs0) * (float)HA;
        const float r1 = (cx - cs1) * (float)HA;

        pixL[tid]  = ((b * HA + iy) * HA + ix) * 96;
        areaL[tid] = fabsf(r0 * r1) + 1e-7f;

        const int row = tid;
        half8 e0;
        e0[0] = (_Float16)r0;  e0[1] = (_Float16)r1;
        e0[2] = (_Float16)cy;  e0[3] = (_Float16)cx;
        e0[4] = (_Float16)rcy; e0[5] = (_Float16)rcx;
        e0[6] = (_Float16)0.f; e0[7] = (_Float16)0.f;
        half8 z = {(_Float16)0.f, (_Float16)0.f, (_Float16)0.f, (_Float16)0.f,
                   (_Float16)0.f, (_Float16)0.f, (_Float16)0.f, (_Float16)0.f};
        *(half8*)&A[row * 128 + ((12 ^ (row & 15)) * 8)] = e0;
        *(half8*)&A[row * 128 + ((13 ^ (row & 15)) * 8)] = z;
        *(half8*)&A[row * 128 + ((14 ^ (row & 15)) * 8)] = z;
        *(half8*)&A[row * 128 + ((15 ^ (row & 15)) * 8)] = z;
    }

    half8 B0[16];
#pragma unroll
    for (int i = 0; i < 16; ++i)
        B0[i] = *(const half8*)(fragTab + ((size_t)i * 64 + lane) * 8);
    float mb0v[4], mb1v[4], w2v[4];
#pragma unroll
    for (int nt = 0; nt < 4; ++nt) {
        mb0v[nt] = mb0[nt * 16 + n_];
        mb1v[nt] = mb1[nt * 16 + n_];
        w2v[nt]  = mw2[nt * 16 + n_];
    }
    const float mb2s = mb2[0];

    __syncthreads();

    {
        const int grp = tid >> 4;
        const int l   = tid & 15;
#pragma unroll 1
        for (int it = 0; it < 8; ++it) {
            const int row  = it * 16 + grp;
            const int base = pixL[row];
            if (l < 12) {
                half8 h = *(const half8*)(asppH + base + l * 8);
                *(half8*)&A[row * 128 + ((l ^ (row & 15)) * 8)] = h;
            }
        }
    }
    __syncthreads();

#pragma unroll 1
    for (int mt = 0; mt < 2; ++mt) {
        const int m0  = wv * 32 + mt * 16;
        const int row = m0 + n_;

        float4v acc[4];
#pragma unroll
        for (int nt = 0; nt < 4; ++nt) {
            float4v t = {mb0v[nt], mb0v[nt], mb0v[nt], mb0v[nt]};
            acc[nt] = t;
        }
#pragma unroll
        for (int kc = 0; kc < 4; ++kc) {
            half8 a = *(const half8*)&A[row * 128 + (((kc * 4 + qd) ^ (row & 15)) * 8)];
#pragma unroll
            for (int nt = 0; nt < 4; ++nt)
                acc[nt] = __builtin_amdgcn_mfma_f32_16x16x32_f16(a, B0[kc * 4 + nt],
                                                                 acc[nt], 0, 0, 0);
        }
#pragma unroll
        for (int nt = 0; nt < 4; ++nt)
#pragma unroll
            for (int reg = 0; reg < 4; ++reg) {
                const int hr = m0 + qd * 4 + reg;
                const int n  = nt * 16 + n_;
                Hb[hr * 64 + (((n >> 3) ^ (hr & 7)) * 8) + (n & 7)] =
                    (_Float16)fmaxf(acc[nt][reg], 0.f);
            }
        __builtin_amdgcn_s_waitcnt(0);

        float4v acc1[4];
#pragma unroll
        for (int nt = 0; nt < 4; ++nt) {
            float4v t = {mb1v[nt], mb1v[nt], mb1v[nt], mb1v[nt]};
            acc1[nt] = t;
        }
#pragma unroll
        for (int kc = 0; kc < 2; ++kc) {
            half8 a1 = *(const half8*)&Hb[row * 64 + (((kc * 4 + qd) ^ (row & 7)) * 8)];
#pragma unroll
            for (int nt = 0; nt < 4; ++nt) {
                half8 b1 = *(const half8*)(fragTab +
                            ((size_t)(16 + kc * 4 + nt) * 64 + lane) * 8);
                acc1[nt] = __builtin_amdgcn_mfma_f32_16x16x32_f16(a1, b1,
                                                                  acc1[nt], 0, 0, 0);
            }
        }

        float p[4];
#pragma unroll
        for (int reg = 0; reg < 4; ++reg) {
            float s = 0.f;
#pragma unroll
            for (int nt = 0; nt < 4; ++nt)
                s = fmaf(fmaxf(acc1[nt][reg], 0.f), w2v[nt], s);
            s += __shfl_xor(s, 1, 64);
            s += __shfl_xor(s, 2, 64);
            s += __shfl_xor(s, 4, 64);
            s += __shfl_xor(s, 8, 64);
            p[reg] = s;
        }
        if (n_ == 0) {
            float4v pv = {p[0] + mb2s, p[1] + mb2s, p[2] + mb2s, p[3] + mb2s};
            *(float4v*)&predL[m0 + qd * 4] = pv;
        }
    }
    __syncthreads();

    if (tid < 32) {
        float4v pr = *(const float4v*)&predL[tid * 4];
        float4v ar = *(const float4v*)&areaL[tid * 4];
        float num = pr[0] * ar[3] + pr[1] * ar[2] + pr[2] * ar[1] + pr[3] * ar[0];
        float den = ar[0] + ar[1] + ar[2] + ar[3];
        out[qidx[r * 32 + tid]] = num / den;
    }
}

// ---------------------------------------------------------------------------
extern "C" void kernel_launch(void* const* d_in, const int* in_sizes, int n_in,
                              void* d_out, int out_size, void* d_ws, size_t ws_size,
                              hipStream_t stream) {
    (void)in_sizes; (void)n_in; (void)out_size; (void)ws_size;
    const float* feats2  = (const float*)d_in[0];
    const float* feats4  = (const float*)d_in[1];
    const float* feats32 = (const float*)d_in[2];
    const float* coords  = (const float*)d_in[3];
    const float* cells   = (const float*)d_in[4];
    const float* w2  = (const float*)d_in[5];
    const float* b2  = (const float*)d_in[6];
    const float* w4  = (const float*)d_in[7];
    const float* b4  = (const float*)d_in[8];
    const float* w32 = (const float*)d_in[9];
    const float* b32 = (const float*)d_in[10];
    const float* wf  = (const float*)d_in[11];
    const float* bf  = (const float*)d_in[12];
    const float* mw0 = (const float*)d_in[13];
    const float* mb0 = (const float*)d_in[14];
    const float* mw1 = (const float*)d_in[15];
    const float* mb1 = (const float*)d_in[16];
    const float* mw2 = (const float*)d_in[17];
    const float* mb2 = (const float*)d_in[18];

    float* ws = (float*)d_ws;
    float*    a4s   = ws;                          // 589824 f
    float*    a32s  = a4s + 589824;                // 36864 f
    _Float16* xcatH = (_Float16*)(a32s + 36864);   // 7,077,888 h
    _Float16* asppH = xcatH + 7077888;             // 7,077,888 h
    _Float16* fragTab  = asppH + 7077888;          // 12,288 h
    _Float16* fragTabW = fragTab + 12288;          // 82,944 h
    float4v*  qdata = (float4v*)(fragTabW + 82944);   // NQ * 16 B
    int*      qidx  = (int*)(qdata + NQ);             // NQ ints
    int*      blockCnt = qidx + NQ;                   // NBKT*NB ints
    int*      blockOff = blockCnt + NBKT * NB;        // NBKT*NB ints
    unsigned char* lrank = (unsigned char*)(blockOff + NBKT * NB);  // NQ bytes
    float* out = (float*)d_out;

    prep_all<<<47, 256, 0, stream>>>(mw0, mw1, wf, fragTab, fragTabW);
    sort_count<<<NB, 256, 0, stream>>>(coords, blockCnt, lrank);
    sort_scan<<<1, 1024, 0, stream>>>(blockCnt, blockOff);
    sort_scatter<<<NB, 256, 0, stream>>>(coords, cells, blockOff, lrank,
                                         qidx, qdata);
    conv1x1_ab<<<2448, 256, 0, stream>>>(feats4, w4, b4, feats32, w32, b32,
                                         a4s, a32s);
    build_xcat<<<dim3(9216, 3), 256, 0, stream>>>(feats2, w2, b2, a4s, a32s,
                                                  xcatH);
    conv3x3_mfma<<<dim3(12, 24, 2), 256, 0, stream>>>(xcatH, fragTabW, bf, asppH);
    decoder_mlp_mfma<<<9216, 256, 0, stream>>>(asppH, qidx, qdata, fragTab,
                                               mb0, mb1, mw2, mb2, out);
}

// Round 10
// 306.769 us; speedup vs baseline: 2.2716x; 2.2716x over previous
//
#include <hip/hip_runtime.h>
#include <math.h>

// ---------------------------------------------------------------------------
// Decoder_82764019794508: LIIF-style decoder.
// R10: parallel scan. R9's single-block sort_scan (1 CU, 324 strided serial
// loads/thread) ran 405 us at 0.04% VALUBusy. Replace with hierarchical scan:
//   sort_count -> cntT[bkt*NB+blk] (bucket-major, scan-ready)
//   scan_chunks: 324 blocks x 1024 thr, LDS scan of contiguous 1024-chunks
//   scan_partials: 1 block scans 324 chunk totals
//   sort_scatter: pos = chunkEx[li>>10] + scanEx[li] + lrank
// Decoder / conv pipeline byte-identical to R9 (same order, same bits).
// ---------------------------------------------------------------------------

#define HQ 384
#define HA 192
#define NQ (2 * HQ * HQ)   // 294912 queries
#define NB (NQ / 256)      // 1152 sort blocks
#define NBKT 288           // 2 batches x 12x12 tiles of 16x16 px
#define NFLAT (NBKT * NB)  // 331776 = 324 * 1024

typedef _Float16 half8  __attribute__((ext_vector_type(8)));
typedef _Float16 half4v __attribute__((ext_vector_type(4)));
typedef float    float4v __attribute__((ext_vector_type(4)));

// bucket id from query coords: corner k=0 (vy=vx=-1) pixel, 16x16 tiles
__device__ __forceinline__ int bucket_id(int q, float cy, float cx) {
    const float LO = -1.0f + 1e-7f, HI = 1.0f - 1e-7f;
    const float RXY = 1.0f / (float)HA;
    float c0 = fminf(fmaxf((cy - RXY) + 1e-7f, LO), HI);
    float c1 = fminf(fmaxf((cx - RXY) + 1e-7f, LO), HI);
    int iy = (int)rintf(((c0 + 1.f) * (float)HA) * 0.5f - 0.5f);
    int ix = (int)rintf(((c1 + 1.f) * (float)HA) * 0.5f - 0.5f);
    iy = min(max(iy, 0), HA - 1);
    ix = min(max(ix, 0), HA - 1);
    int b = q / (HQ * HQ);
    return b * 144 + (iy >> 4) * 12 + (ix >> 4);
}

// ---- K0: pack ALL weights into per-lane MFMA B-fragments ------------------
__global__ void prep_all(const float* __restrict__ mw0,
                         const float* __restrict__ mw1,
                         const float* __restrict__ wf,
                         _Float16* __restrict__ fragTab,
                         _Float16* __restrict__ fragTabW) {
    int t = blockIdx.x * 256 + threadIdx.x;
    if (t < 1536) {
        int f = t >> 6, L = t & 63;
        int n_ = L & 15, qd = L >> 4;
        _Float16 vals[8];
        if (f < 16) {
            int kc = f >> 2, nt = f & 3;
#pragma unroll
            for (int j = 0; j < 8; ++j) {
                int kk = kc * 32 + qd * 8 + j;
                vals[j] = (_Float16)((kk < 102) ? mw0[kk * 64 + nt * 16 + n_] : 0.f);
            }
        } else {
            int g = f - 16;
            int kc = g >> 2, nt = g & 3;
#pragma unroll
            for (int j = 0; j < 8; ++j) {
                int kk = kc * 32 + qd * 8 + j;
                vals[j] = (_Float16)mw1[kk * 64 + nt * 16 + n_];
            }
        }
#pragma unroll
        for (int j = 0; j < 8; ++j) fragTab[t * 8 + j] = vals[j];
    } else {
        int tw = t - 1536;
        if (tw >= 27 * 6 * 64) return;
        int s   = tw / 384;
        int rem = tw - s * 384;
        int nt  = rem >> 6;
        int L   = rem & 63;
        int n_  = L & 15, qd = L >> 4;
        int tap = s / 3, kc = s - tap * 3;
#pragma unroll
        for (int j = 0; j < 8; ++j) {
            int kch = kc * 32 + qd * 8 + j;
            fragTabW[tw * 8 + j] = (_Float16)wf[(tap * 96 + kch) * 96 + nt * 16 + n_];
        }
    }
}

// ---- K_s1: per-block LDS histogram + local rank; counts stored transposed -
__global__ void sort_count(const float* __restrict__ coords,
                           int* __restrict__ cntT,
                           unsigned char* __restrict__ lrank) {
    __shared__ int lh[NBKT];
    const int tid = threadIdx.x;
    for (int i = tid; i < NBKT; i += 256) lh[i] = 0;
    __syncthreads();
    const int q = blockIdx.x * 256 + tid;
    float cy = coords[(size_t)q * 2 + 0];
    float cx = coords[(size_t)q * 2 + 1];
    int r = atomicAdd(&lh[bucket_id(q, cy, cx)], 1);   // LDS atomic only
    lrank[q] = (unsigned char)r;
    __syncthreads();
    for (int i = tid; i < NBKT; i += 256)
        cntT[i * NB + blockIdx.x] = lh[i];             // bucket-major layout
}

// ---- K_s2a: per-1024-chunk exclusive scan (coalesced, LDS Hillis-Steele) --
__global__ void scan_chunks(const int* __restrict__ cntT,
                            int* __restrict__ scanEx,
                            int* __restrict__ partials) {
    __shared__ int s[1024];
    const int t = threadIdx.x;
    const int gi = blockIdx.x * 1024 + t;
    int v = cntT[gi];
    s[t] = v;
    __syncthreads();
    for (int off = 1; off < 1024; off <<= 1) {
        int x = (t >= off) ? s[t - off] : 0;
        __syncthreads();
        s[t] += x;
        __syncthreads();
    }
    scanEx[gi] = s[t] - v;                 // exclusive within chunk
    if (t == 1023) partials[blockIdx.x] = s[t];
}

// ---- K_s2b: exclusive scan of 324 chunk totals ----------------------------
__global__ void scan_partials(int* __restrict__ partials) {
    __shared__ int s[512];
    const int t = threadIdx.x;
    int v = (t < 324) ? partials[t] : 0;
    s[t] = v;
    __syncthreads();
    for (int off = 1; off < 512; off <<= 1) {
        int x = (t >= off) ? s[t - off] : 0;
        __syncthreads();
        s[t] += x;
        __syncthreads();
    }
    if (t < 324) partials[t] = s[t] - v;   // in-place exclusive
}

// ---- K_s3: scatter query indices + packed per-query data (no atomics) -----
__global__ void sort_scatter(const float* __restrict__ coords,
                             const float* __restrict__ cells,
                             const int* __restrict__ scanEx,
                             const int* __restrict__ partials,
                             const unsigned char* __restrict__ lrank,
                             int* __restrict__ qidx,
                             float4v* __restrict__ qdata) {
    const int q = blockIdx.x * 256 + threadIdx.x;
    float cy = coords[(size_t)q * 2 + 0];
    float cx = coords[(size_t)q * 2 + 1];
    int bkt = bucket_id(q, cy, cx);
    int li  = bkt * NB + blockIdx.x;
    int pos = partials[li >> 10] + scanEx[li] + (int)lrank[q];
    qidx[pos] = q;
    float4v d = {cy, cx,
                 cells[(size_t)q * 2 + 0] * (float)HA,
                 cells[(size_t)q * 2 + 1] * (float)HA};
    qdata[pos] = d;
}

// ---- K1: fused 1x1 convs for a4s (96->32) and a32s (160->32), fp32 out ----
__global__ void conv1x1_ab(const float* __restrict__ feats4,
                           const float* __restrict__ w4,
                           const float* __restrict__ b4,
                           const float* __restrict__ feats32,
                           const float* __restrict__ w32,
                           const float* __restrict__ b32,
                           float* __restrict__ a4s,
                           float* __restrict__ a32s) {
    int blk = blockIdx.x;
    if (blk < 2304) {
        int t = blk * 256 + threadIdx.x;
        int p = t >> 5, c = t & 31;
        const float* xr = feats4 + (size_t)p * 96;
        float acc = b4[c];
#pragma unroll
        for (int i = 0; i < 96; ++i) acc = fmaf(xr[i], w4[i * 32 + c], acc);
        a4s[(size_t)p * 32 + c] = fmaxf(acc, 0.f);
    } else {
        int t = (blk - 2304) * 256 + threadIdx.x;
        int p = t >> 5, c = t & 31;
        const float* xr = feats32 + (size_t)p * 160;
        float acc = b32[c];
#pragma unroll
        for (int i = 0; i < 160; ++i) acc = fmaf(xr[i], w32[i * 32 + c], acc);
        a32s[(size_t)p * 32 + c] = fmaxf(acc, 0.f);
    }
}

// ---- K2: build xcat (fp16), 3 slices selected by blockIdx.y ---------------
__global__ void build_xcat(const float* __restrict__ feats2,
                           const float* __restrict__ w2,
                           const float* __restrict__ b2,
                           const float* __restrict__ a4s,
                           const float* __restrict__ a32s,
                           _Float16* __restrict__ xcatH) {
    const int z = blockIdx.y;
    int t = blockIdx.x * 256 + threadIdx.x;
    int c = t & 31;
    int p = t >> 5;

    if (z == 0) {
        const float* xr = feats2 + (size_t)p * 64;
        float acc = b2[c];
#pragma unroll
        for (int i = 0; i < 64; ++i) acc = fmaf(xr[i], w2[i * 32 + c], acc);
        xcatH[(size_t)p * 96 + c] = (_Float16)fmaxf(acc, 0.f);
        return;
    }

    const float* src = (z == 1) ? a4s : a32s;
    const int   S    = (z == 1) ? 96 : 24;
    const float inv  = (z == 1) ? 0.5f : 0.125f;
    const int   coff = (z == 1) ? 32 : 64;

    int x = p % HA;
    int r = p / HA;
    int y = r % HA;
    int b = r / HA;

    float u = ((float)y + 0.5f) * inv - 0.5f;
    float v = ((float)x + 0.5f) * inv - 0.5f;
    float fu = floorf(u), fv = floorf(v);
    float wu = u - fu, wv = v - fv;
    int y0 = (int)fu, x0 = (int)fv;
    int y1 = min(y0 + 1, S - 1);
    int x1 = min(x0 + 1, S - 1);
    y0 = max(y0, 0);
    x0 = max(x0, 0);

    const float* sb = src + (size_t)b * S * S * 32 + c;
    float v00 = sb[(y0 * S + x0) * 32];
    float v01 = sb[(y0 * S + x1) * 32];
    float v10 = sb[(y1 * S + x0) * 32];
    float v11 = sb[(y1 * S + x1) * 32];
    float t0 = v00 * (1.f - wu) + v10 * wu;
    float t1 = v01 * (1.f - wu) + v11 * wu;
    float o  = t0 * (1.f - wv) + t1 * wv;
    xcatH[(size_t)p * 96 + coff + c] = (_Float16)o;
}

// ---- K3: 3x3 conv 96->96 + bias + ReLU via fp16 MFMA, fp16 in/out ---------
__launch_bounds__(256, 4)
__global__ void conv3x3_mfma(const _Float16* __restrict__ xH,
                             const _Float16* __restrict__ fragTabW,
                             const float* __restrict__ bias,
                             _Float16* __restrict__ yH) {
    __shared__ _Float16 lds[10 * 18 * 104];
    const int tid = threadIdx.x;
    const int lane = tid & 63;
    const int wv   = tid >> 6;
    const int n_   = lane & 15;
    const int qd   = lane >> 4;
    const int nh   = wv & 1;
    const int yg   = wv >> 1;
    const int bx0  = blockIdx.x * 16;
    const int by0  = blockIdx.y * 8;
    const int b    = blockIdx.z;

    for (int idx = tid; idx < 2160; idx += 256) {
        int hy  = idx / 216;
        int rem = idx - hy * 216;
        int hx  = rem / 12;
        int cc  = rem - hx * 12;
        int gy = by0 + hy - 1, gx = bx0 + hx - 1;
        half8 v = {(_Float16)0.f, (_Float16)0.f, (_Float16)0.f, (_Float16)0.f,
                   (_Float16)0.f, (_Float16)0.f, (_Float16)0.f, (_Float16)0.f};
        if (gy >= 0 && gy < HA && gx >= 0 && gx < HA)
            v = *(const half8*)(xH + (((size_t)b * HA + gy) * HA + gx) * 96 + cc * 8);
        *(half8*)&lds[(hy * 18 + hx) * 104 + cc * 8] = v;
    }

    float bv[3];
#pragma unroll
    for (int j = 0; j < 3; ++j) bv[j] = bias[(nh * 3 + j) * 16 + n_];

    __syncthreads();

    float4v acc[4][3];
#pragma unroll
    for (int r = 0; r < 4; ++r)
#pragma unroll
        for (int j = 0; j < 3; ++j) {
            float4v z = {0.f, 0.f, 0.f, 0.f};
            acc[r][j] = z;
        }

#pragma unroll 1
    for (int ky = 0; ky < 3; ++ky)
#pragma unroll 1
        for (int kx = 0; kx < 3; ++kx) {
            const int tap = ky * 3 + kx;
#pragma unroll
            for (int kc = 0; kc < 3; ++kc) {
                const int s = tap * 3 + kc;
                half8 bf[3];
#pragma unroll
                for (int j = 0; j < 3; ++j)
                    bf[j] = *(const half8*)(fragTabW +
                            ((size_t)(s * 6 + nh * 3 + j) * 64 + lane) * 8);
#pragma unroll
                for (int r = 0; r < 4; ++r) {
                    const int yr = yg * 4 + r;
                    half8 a = *(const half8*)&lds[((yr + ky) * 18 + (n_ + kx)) * 104
                                                  + kc * 32 + qd * 8];
#pragma unroll
                    for (int j = 0; j < 3; ++j)
                        acc[r][j] = __builtin_amdgcn_mfma_f32_16x16x32_f16(
                            a, bf[j], acc[r][j], 0, 0, 0);
                }
            }
        }

#pragma unroll
    for (int r = 0; r < 4; ++r) {
        const int gy = by0 + yg * 4 + r;
#pragma unroll
        for (int j = 0; j < 3; ++j) {
            const int ch = (nh * 3 + j) * 16 + n_;
#pragma unroll
            for (int reg = 0; reg < 4; ++reg) {
                const int gx = bx0 + qd * 4 + reg;
                yH[(((size_t)b * HA + gy) * HA + gx) * 96 + ch] =
                    (_Float16)fmaxf(acc[r][j][reg] + bv[j], 0.f);
            }
        }
    }
}

// ---- K4: sorted 4-corner gather + MLP ensemble via fp16 MFMA --------------
__launch_bounds__(256, 3)
__global__ void decoder_mlp_mfma(const _Float16* __restrict__ asppH,
                                 const int* __restrict__ qidx,
                                 const float4v* __restrict__ qdata,
                                 const _Float16* __restrict__ fragTab,
                                 const float* __restrict__ mb0,
                                 const float* __restrict__ mb1,
                                 const float* __restrict__ mw2,
                                 const float* __restrict__ mb2,
                                 float* __restrict__ out) {
    __shared__ __align__(16) unsigned char smem[50688];
    _Float16* A   = (_Float16*)smem;              // 32768 B
    _Float16* Hb  = (_Float16*)(smem + 32768);    // 16384 B
    int*      pixL  = (int*)(smem + 49152);       // 512 B
    float*    areaL = (float*)(smem + 49664);     // 512 B
    float*    predL = (float*)(smem + 50176);     // 512 B

    const int tid  = threadIdx.x;
    const int lane = tid & 63;
    const int wv   = tid >> 6;
    const int n_   = lane & 15;
    const int qd   = lane >> 4;
    const int r    = (blockIdx.x & 7) * 1152 + (blockIdx.x >> 3);

    if (tid < 128) {
        const int lq = tid >> 2, k = tid & 3;
        const int sp = r * 32 + lq;
        const float4v d = qdata[sp];
        const int qq = qidx[sp];
        const int b  = qq / (HQ * HQ);
        const float cy = d[0], cx = d[1];
        const float rcy = d[2], rcx = d[3];

        const float LO = -1.0f + 1e-7f, HI = 1.0f - 1e-7f;
        const float RXY = 1.0f / (float)HA;
        const float vy = (k < 2) ? -1.f : 1.f;
        const float vx = (k & 1) ? 1.f : -1.f;

        float c0 = fminf(fmaxf((cy + vy * RXY) + 1e-7f, LO), HI);
        float c1 = fminf(fmaxf((cx + vx * RXY) + 1e-7f, LO), HI);
        int iy = (int)rintf(((c0 + 1.f) * (float)HA) * 0.5f - 0.5f);
        int ix = (int)rintf(((c1 + 1.f) * (float)HA) * 0.5f - 0.5f);
        iy = min(max(iy, 0), HA - 1);
        ix = min(max(ix, 0), HA - 1);

        const float cs0 = (((float)iy + 0.5f) / (float)HA) * 2.f - 1.f;
        const float cs1 = (((float)ix + 0.5f) / (float)HA) * 2.f - 1.f;
        const float r0 = (cy - cs0) * (float)HA;
        const float r1 = (cx - cs1) * (float)HA;

        pixL[tid]  = ((b * HA + iy) * HA + ix) * 96;
        areaL[tid] = fabsf(r0 * r1) + 1e-7f;

        const int row = tid;
        half8 e0;
        e0[0] = (_Float16)r0;  e0[1] = (_Float16)r1;
        e0[2] = (_Float16)cy;  e0[3] = (_Float16)cx;
        e0[4] = (_Float16)rcy; e0[5] = (_Float16)rcx;
        e0[6] = (_Float16)0.f; e0[7] = (_Float16)0.f;
        half8 z = {(_Float16)0.f, (_Float16)0.f, (_Float16)0.f, (_Float16)0.f,
                   (_Float16)0.f, (_Float16)0.f, (_Float16)0.f, (_Float16)0.f};
        *(half8*)&A[row * 128 + ((12 ^ (row & 15)) * 8)] = e0;
        *(half8*)&A[row * 128 + ((13 ^ (row & 15)) * 8)] = z;
        *(half8*)&A[row * 128 + ((14 ^ (row & 15)) * 8)] = z;
        *(half8*)&A[row * 128 + ((15 ^ (row & 15)) * 8)] = z;
    }

    half8 B0[16];
#pragma unroll
    for (int i = 0; i < 16; ++i)
        B0[i] = *(const half8*)(fragTab + ((size_t)i * 64 + lane) * 8);
    float mb0v[4], mb1v[4], w2v[4];
#pragma unroll
    for (int nt = 0; nt < 4; ++nt) {
        mb0v[nt] = mb0[nt * 16 + n_];
        mb1v[nt] = mb1[nt * 16 + n_];
        w2v[nt]  = mw2[nt * 16 + n_];
    }
    const float mb2s = mb2[0];

    __syncthreads();

    {
        const int grp = tid >> 4;
        const int l   = tid & 15;
#pragma unroll 1
        for (int it = 0; it < 8; ++it) {
            const int row  = it * 16 + grp;
            const int base = pixL[row];
            if (l < 12) {
                half8 h = *(const half8*)(asppH + base + l * 8);
                *(half8*)&A[row * 128 + ((l ^ (row & 15)) * 8)] = h;
            }
        }
    }
    __syncthreads();

#pragma unroll 1
    for (int mt = 0; mt < 2; ++mt) {
        const int m0  = wv * 32 + mt * 16;
        const int row = m0 + n_;

        float4v acc[4];
#pragma unroll
        for (int nt = 0; nt < 4; ++nt) {
            float4v t = {mb0v[nt], mb0v[nt], mb0v[nt], mb0v[nt]};
            acc[nt] = t;
        }
#pragma unroll
        for (int kc = 0; kc < 4; ++kc) {
            half8 a = *(const half8*)&A[row * 128 + (((kc * 4 + qd) ^ (row & 15)) * 8)];
#pragma unroll
            for (int nt = 0; nt < 4; ++nt)
                acc[nt] = __builtin_amdgcn_mfma_f32_16x16x32_f16(a, B0[kc * 4 + nt],
                                                                 acc[nt], 0, 0, 0);
        }
#pragma unroll
        for (int nt = 0; nt < 4; ++nt)
#pragma unroll
            for (int reg = 0; reg < 4; ++reg) {
                const int hr = m0 + qd * 4 + reg;
                const int n  = nt * 16 + n_;
                Hb[hr * 64 + (((n >> 3) ^ (hr & 7)) * 8) + (n & 7)] =
                    (_Float16)fmaxf(acc[nt][reg], 0.f);
            }
        __builtin_amdgcn_s_waitcnt(0);

        float4v acc1[4];
#pragma unroll
        for (int nt = 0; nt < 4; ++nt) {
            float4v t = {mb1v[nt], mb1v[nt], mb1v[nt], mb1v[nt]};
            acc1[nt] = t;
        }
#pragma unroll
        for (int kc = 0; kc < 2; ++kc) {
            half8 a1 = *(const half8*)&Hb[row * 64 + (((kc * 4 + qd) ^ (row & 7)) * 8)];
#pragma unroll
            for (int nt = 0; nt < 4; ++nt) {
                half8 b1 = *(const half8*)(fragTab +
                            ((size_t)(16 + kc * 4 + nt) * 64 + lane) * 8);
                acc1[nt] = __builtin_amdgcn_mfma_f32_16x16x32_f16(a1, b1,
                                                                  acc1[nt], 0, 0, 0);
            }
        }

        float p[4];
#pragma unroll
        for (int reg = 0; reg < 4; ++reg) {
            float s = 0.f;
#pragma unroll
            for (int nt = 0; nt < 4; ++nt)
                s = fmaf(fmaxf(acc1[nt][reg], 0.f), w2v[nt], s);
            s += __shfl_xor(s, 1, 64);
            s += __shfl_xor(s, 2, 64);
            s += __shfl_xor(s, 4, 64);
            s += __shfl_xor(s, 8, 64);
            p[reg] = s;
        }
        if (n_ == 0) {
            float4v pv = {p[0] + mb2s, p[1] + mb2s, p[2] + mb2s, p[3] + mb2s};
            *(float4v*)&predL[m0 + qd * 4] = pv;
        }
    }
    __syncthreads();

    if (tid < 32) {
        float4v pr = *(const float4v*)&predL[tid * 4];
        float4v ar = *(const float4v*)&areaL[tid * 4];
        float num = pr[0] * ar[3] + pr[1] * ar[2] + pr[2] * ar[1] + pr[3] * ar[0];
        float den = ar[0] + ar[1] + ar[2] + ar[3];
        out[qidx[r * 32 + tid]] = num / den;
    }
}

// ---------------------------------------------------------------------------
extern "C" void kernel_launch(void* const* d_in, const int* in_sizes, int n_in,
                              void* d_out, int out_size, void* d_ws, size_t ws_size,
                              hipStream_t stream) {
    (void)in_sizes; (void)n_in; (void)out_size; (void)ws_size;
    const float* feats2  = (const float*)d_in[0];
    const float* feats4  = (const float*)d_in[1];
    const float* feats32 = (const float*)d_in[2];
    const float* coords  = (const float*)d_in[3];
    const float* cells   = (const float*)d_in[4];
    const float* w2  = (const float*)d_in[5];
    const float* b2  = (const float*)d_in[6];
    const float* w4  = (const float*)d_in[7];
    const float* b4  = (const float*)d_in[8];
    const float* w32 = (const float*)d_in[9];
    const float* b32 = (const float*)d_in[10];
    const float* wf  = (const float*)d_in[11];
    const float* bf  = (const float*)d_in[12];
    const float* mw0 = (const float*)d_in[13];
    const float* mb0 = (const float*)d_in[14];
    const float* mw1 = (const float*)d_in[15];
    const float* mb1 = (const float*)d_in[16];
    const float* mw2 = (const float*)d_in[17];
    const float* mb2 = (const float*)d_in[18];

    float* ws = (float*)d_ws;
    float*    a4s   = ws;                          // 589824 f
    float*    a32s  = a4s + 589824;                // 36864 f
    _Float16* xcatH = (_Float16*)(a32s + 36864);   // 7,077,888 h
    _Float16* asppH = xcatH + 7077888;             // 7,077,888 h
    _Float16* fragTab  = asppH + 7077888;          // 12,288 h
    _Float16* fragTabW = fragTab + 12288;          // 82,944 h
    float4v*  qdata = (float4v*)(fragTabW + 82944);   // NQ * 16 B
    int*      qidx  = (int*)(qdata + NQ);             // NQ ints
    int*      cntT  = qidx + NQ;                      // NFLAT ints
    int*      scanEx = cntT + NFLAT;                  // NFLAT ints
    int*      partials = scanEx + NFLAT;              // 324 ints
    unsigned char* lrank = (unsigned char*)(partials + 324);  // NQ bytes
    float* out = (float*)d_out;

    prep_all<<<47, 256, 0, stream>>>(mw0, mw1, wf, fragTab, fragTabW);
    sort_count<<<NB, 256, 0, stream>>>(coords, cntT, lrank);
    scan_chunks<<<NFLAT / 1024, 1024, 0, stream>>>(cntT, scanEx, partials);
    scan_partials<<<1, 512, 0, stream>>>(partials);
    sort_scatter<<<NB, 256, 0, stream>>>(coords, cells, scanEx, partials,
                                         lrank, qidx, qdata);
    conv1x1_ab<<<2448, 256, 0, stream>>>(feats4, w4, b4, feats32, w32, b32,
                                         a4s, a32s);
    build_xcat<<<dim3(9216, 3), 256, 0, stream>>>(feats2, w2, b2, a4s, a32s,
                                                  xcatH);
    conv3x3_mfma<<<dim3(12, 24, 2), 256, 0, stream>>>(xcatH, fragTabW, bf, asppH);
    decoder_mlp_mfma<<<9216, 256, 0, stream>>>(asppH, qidx, qdata, fragTab,
                                               mb0, mb1, mw2, mb2, out);
}

// Round 11
// 270.148 us; speedup vs baseline: 2.5795x; 1.1356x over previous
//
#include <hip/hip_runtime.h>
#include <math.h>

// ---------------------------------------------------------------------------
// Decoder_82764019794508: LIIF-style decoder.
// R11: decoder occupancy (R10: 118us @ 31% occupancy, latency-bound; FETCH
// 14.8MB == one aspp pass, so locality is done). Block halved to 64 rows
// (16 queries): LDS 50.7->24.8 KB, launch_bounds(256,5) -> 5 blocks/CU
// (20 waves/CU vs 12). conv1x1_ab/build_xcat: 4 ch/thread, float4 loads.
// All numerics bit-identical to R10.
// ---------------------------------------------------------------------------

#define HQ 384
#define HA 192
#define NQ (2 * HQ * HQ)   // 294912 queries
#define NB (NQ / 256)      // 1152 sort blocks
#define NBKT 288           // 2 batches x 12x12 tiles of 16x16 px
#define NFLAT (NBKT * NB)  // 331776 = 324 * 1024

typedef _Float16 half8  __attribute__((ext_vector_type(8)));
typedef _Float16 half4v __attribute__((ext_vector_type(4)));
typedef float    float4v __attribute__((ext_vector_type(4)));

// bucket id from query coords: corner k=0 (vy=vx=-1) pixel, 16x16 tiles
__device__ __forceinline__ int bucket_id(int q, float cy, float cx) {
    const float LO = -1.0f + 1e-7f, HI = 1.0f - 1e-7f;
    const float RXY = 1.0f / (float)HA;
    float c0 = fminf(fmaxf((cy - RXY) + 1e-7f, LO), HI);
    float c1 = fminf(fmaxf((cx - RXY) + 1e-7f, LO), HI);
    int iy = (int)rintf(((c0 + 1.f) * (float)HA) * 0.5f - 0.5f);
    int ix = (int)rintf(((c1 + 1.f) * (float)HA) * 0.5f - 0.5f);
    iy = min(max(iy, 0), HA - 1);
    ix = min(max(ix, 0), HA - 1);
    int b = q / (HQ * HQ);
    return b * 144 + (iy >> 4) * 12 + (ix >> 4);
}

// ---- K0: pack ALL weights into per-lane MFMA B-fragments ------------------
__global__ void prep_all(const float* __restrict__ mw0,
                         const float* __restrict__ mw1,
                         const float* __restrict__ wf,
                         _Float16* __restrict__ fragTab,
                         _Float16* __restrict__ fragTabW) {
    int t = blockIdx.x * 256 + threadIdx.x;
    if (t < 1536) {
        int f = t >> 6, L = t & 63;
        int n_ = L & 15, qd = L >> 4;
        _Float16 vals[8];
        if (f < 16) {
            int kc = f >> 2, nt = f & 3;
#pragma unroll
            for (int j = 0; j < 8; ++j) {
                int kk = kc * 32 + qd * 8 + j;
                vals[j] = (_Float16)((kk < 102) ? mw0[kk * 64 + nt * 16 + n_] : 0.f);
            }
        } else {
            int g = f - 16;
            int kc = g >> 2, nt = g & 3;
#pragma unroll
            for (int j = 0; j < 8; ++j) {
                int kk = kc * 32 + qd * 8 + j;
                vals[j] = (_Float16)mw1[kk * 64 + nt * 16 + n_];
            }
        }
#pragma unroll
        for (int j = 0; j < 8; ++j) fragTab[t * 8 + j] = vals[j];
    } else {
        int tw = t - 1536;
        if (tw >= 27 * 6 * 64) return;
        int s   = tw / 384;
        int rem = tw - s * 384;
        int nt  = rem >> 6;
        int L   = rem & 63;
        int n_  = L & 15, qd = L >> 4;
        int tap = s / 3, kc = s - tap * 3;
#pragma unroll
        for (int j = 0; j < 8; ++j) {
            int kch = kc * 32 + qd * 8 + j;
            fragTabW[tw * 8 + j] = (_Float16)wf[(tap * 96 + kch) * 96 + nt * 16 + n_];
        }
    }
}

// ---- K_s1: per-block LDS histogram + local rank; counts stored transposed -
__global__ void sort_count(const float* __restrict__ coords,
                           int* __restrict__ cntT,
                           unsigned char* __restrict__ lrank) {
    __shared__ int lh[NBKT];
    const int tid = threadIdx.x;
    for (int i = tid; i < NBKT; i += 256) lh[i] = 0;
    __syncthreads();
    const int q = blockIdx.x * 256 + tid;
    float cy = coords[(size_t)q * 2 + 0];
    float cx = coords[(size_t)q * 2 + 1];
    int r = atomicAdd(&lh[bucket_id(q, cy, cx)], 1);   // LDS atomic only
    lrank[q] = (unsigned char)r;
    __syncthreads();
    for (int i = tid; i < NBKT; i += 256)
        cntT[i * NB + blockIdx.x] = lh[i];             // bucket-major layout
}

// ---- K_s2a: per-1024-chunk exclusive scan (coalesced, LDS Hillis-Steele) --
__global__ void scan_chunks(const int* __restrict__ cntT,
                            int* __restrict__ scanEx,
                            int* __restrict__ partials) {
    __shared__ int s[1024];
    const int t = threadIdx.x;
    const int gi = blockIdx.x * 1024 + t;
    int v = cntT[gi];
    s[t] = v;
    __syncthreads();
    for (int off = 1; off < 1024; off <<= 1) {
        int x = (t >= off) ? s[t - off] : 0;
        __syncthreads();
        s[t] += x;
        __syncthreads();
    }
    scanEx[gi] = s[t] - v;                 // exclusive within chunk
    if (t == 1023) partials[blockIdx.x] = s[t];
}

// ---- K_s2b: exclusive scan of 324 chunk totals ----------------------------
__global__ void scan_partials(int* __restrict__ partials) {
    __shared__ int s[512];
    const int t = threadIdx.x;
    int v = (t < 324) ? partials[t] : 0;
    s[t] = v;
    __syncthreads();
    for (int off = 1; off < 512; off <<= 1) {
        int x = (t >= off) ? s[t - off] : 0;
        __syncthreads();
        s[t] += x;
        __syncthreads();
    }
    if (t < 324) partials[t] = s[t] - v;   // in-place exclusive
}

// ---- K_s3: scatter query indices + packed per-query data (no atomics) -----
__global__ void sort_scatter(const float* __restrict__ coords,
                             const float* __restrict__ cells,
                             const int* __restrict__ scanEx,
                             const int* __restrict__ partials,
                             const unsigned char* __restrict__ lrank,
                             int* __restrict__ qidx,
                             float4v* __restrict__ qdata) {
    const int q = blockIdx.x * 256 + threadIdx.x;
    float cy = coords[(size_t)q * 2 + 0];
    float cx = coords[(size_t)q * 2 + 1];
    int bkt = bucket_id(q, cy, cx);
    int li  = bkt * NB + blockIdx.x;
    int pos = partials[li >> 10] + scanEx[li] + (int)lrank[q];
    qidx[pos] = q;
    float4v d = {cy, cx,
                 cells[(size_t)q * 2 + 0] * (float)HA,
                 cells[(size_t)q * 2 + 1] * (float)HA};
    qdata[pos] = d;
}

// ---- K1: fused 1x1 convs, 4 output channels per thread --------------------
__global__ void conv1x1_ab(const float* __restrict__ feats4,
                           const float* __restrict__ w4,
                           const float* __restrict__ b4,
                           const float* __restrict__ feats32,
                           const float* __restrict__ w32,
                           const float* __restrict__ b32,
                           float* __restrict__ a4s,
                           float* __restrict__ a32s) {
    int blk = blockIdx.x;
    if (blk < 576) {                       // 18432 px * 8 thr
        int t = blk * 256 + threadIdx.x;
        int p = t >> 3, cg = t & 7;
        const float4v* xr = (const float4v*)(feats4 + (size_t)p * 96);
        float4v acc = *(const float4v*)(b4 + cg * 4);
#pragma unroll
        for (int i4 = 0; i4 < 24; ++i4) {
            float4v xv = xr[i4];
            const float* wr = w4 + (i4 * 4) * 32 + cg * 4;
#pragma unroll
            for (int j = 0; j < 4; ++j) {
                float4v wv = *(const float4v*)(wr + j * 32);
                acc[0] = fmaf(xv[j], wv[0], acc[0]);
                acc[1] = fmaf(xv[j], wv[1], acc[1]);
                acc[2] = fmaf(xv[j], wv[2], acc[2]);
                acc[3] = fmaf(xv[j], wv[3], acc[3]);
            }
        }
        float4v o = {fmaxf(acc[0], 0.f), fmaxf(acc[1], 0.f),
                     fmaxf(acc[2], 0.f), fmaxf(acc[3], 0.f)};
        *(float4v*)(a4s + (size_t)p * 32 + cg * 4) = o;
    } else {                               // 1152 px * 8 thr = 36 blocks
        int t = (blk - 576) * 256 + threadIdx.x;
        if (t >= 1152 * 8) return;
        int p = t >> 3, cg = t & 7;
        const float4v* xr = (const float4v*)(feats32 + (size_t)p * 160);
        float4v acc = *(const float4v*)(b32 + cg * 4);
#pragma unroll
        for (int i4 = 0; i4 < 40; ++i4) {
            float4v xv = xr[i4];
            const float* wr = w32 + (i4 * 4) * 32 + cg * 4;
#pragma unroll
            for (int j = 0; j < 4; ++j) {
                float4v wv = *(const float4v*)(wr + j * 32);
                acc[0] = fmaf(xv[j], wv[0], acc[0]);
                acc[1] = fmaf(xv[j], wv[1], acc[1]);
                acc[2] = fmaf(xv[j], wv[2], acc[2]);
                acc[3] = fmaf(xv[j], wv[3], acc[3]);
            }
        }
        float4v o = {fmaxf(acc[0], 0.f), fmaxf(acc[1], 0.f),
                     fmaxf(acc[2], 0.f), fmaxf(acc[3], 0.f)};
        *(float4v*)(a32s + (size_t)p * 32 + cg * 4) = o;
    }
}

// ---- K2: build xcat (fp16), 4 channels per thread, 3 slices ---------------
__global__ void build_xcat(const float* __restrict__ feats2,
                           const float* __restrict__ w2,
                           const float* __restrict__ b2,
                           const float* __restrict__ a4s,
                           const float* __restrict__ a32s,
                           _Float16* __restrict__ xcatH) {
    const int z = blockIdx.y;
    int t = blockIdx.x * 256 + threadIdx.x;     // 2304 blocks: 73728 px * 8
    int p = t >> 3, cg = t & 7;

    if (z == 0) {
        const float4v* xr = (const float4v*)(feats2 + (size_t)p * 64);
        float4v acc = *(const float4v*)(b2 + cg * 4);
#pragma unroll
        for (int i4 = 0; i4 < 16; ++i4) {
            float4v xv = xr[i4];
            const float* wr = w2 + (i4 * 4) * 32 + cg * 4;
#pragma unroll
            for (int j = 0; j < 4; ++j) {
                float4v wv = *(const float4v*)(wr + j * 32);
                acc[0] = fmaf(xv[j], wv[0], acc[0]);
                acc[1] = fmaf(xv[j], wv[1], acc[1]);
                acc[2] = fmaf(xv[j], wv[2], acc[2]);
                acc[3] = fmaf(xv[j], wv[3], acc[3]);
            }
        }
        half4v h;
        h[0] = (_Float16)fmaxf(acc[0], 0.f);
        h[1] = (_Float16)fmaxf(acc[1], 0.f);
        h[2] = (_Float16)fmaxf(acc[2], 0.f);
        h[3] = (_Float16)fmaxf(acc[3], 0.f);
        *(half4v*)(xcatH + (size_t)p * 96 + cg * 4) = h;
        return;
    }

    const float* src = (z == 1) ? a4s : a32s;
    const int   S    = (z == 1) ? 96 : 24;
    const float inv  = (z == 1) ? 0.5f : 0.125f;
    const int   coff = (z == 1) ? 32 : 64;

    int x = p % HA;
    int r = p / HA;
    int y = r % HA;
    int b = r / HA;

    float u = ((float)y + 0.5f) * inv - 0.5f;
    float v = ((float)x + 0.5f) * inv - 0.5f;
    float fu = floorf(u), fv = floorf(v);
    float wu = u - fu, wv = v - fv;
    int y0 = (int)fu, x0 = (int)fv;
    int y1 = min(y0 + 1, S - 1);
    int x1 = min(x0 + 1, S - 1);
    y0 = max(y0, 0);
    x0 = max(x0, 0);

    const float* sb = src + (size_t)b * S * S * 32 + cg * 4;
    float4v v00 = *(const float4v*)(sb + (y0 * S + x0) * 32);
    float4v v01 = *(const float4v*)(sb + (y0 * S + x1) * 32);
    float4v v10 = *(const float4v*)(sb + (y1 * S + x0) * 32);
    float4v v11 = *(const float4v*)(sb + (y1 * S + x1) * 32);
    half4v h;
#pragma unroll
    for (int j = 0; j < 4; ++j) {
        float t0 = v00[j] * (1.f - wu) + v10[j] * wu;
        float t1 = v01[j] * (1.f - wu) + v11[j] * wu;
        h[j] = (_Float16)(t0 * (1.f - wv) + t1 * wv);
    }
    *(half4v*)(xcatH + (size_t)p * 96 + coff + cg * 4) = h;
}

// ---- K3: 3x3 conv 96->96 + bias + ReLU via fp16 MFMA, fp16 in/out ---------
__launch_bounds__(256, 4)
__global__ void conv3x3_mfma(const _Float16* __restrict__ xH,
                             const _Float16* __restrict__ fragTabW,
                             const float* __restrict__ bias,
                             _Float16* __restrict__ yH) {
    __shared__ _Float16 lds[10 * 18 * 104];
    const int tid = threadIdx.x;
    const int lane = tid & 63;
    const int wv   = tid >> 6;
    const int n_   = lane & 15;
    const int qd   = lane >> 4;
    const int nh   = wv & 1;
    const int yg   = wv >> 1;
    const int bx0  = blockIdx.x * 16;
    const int by0  = blockIdx.y * 8;
    const int b    = blockIdx.z;

    for (int idx = tid; idx < 2160; idx += 256) {
        int hy  = idx / 216;
        int rem = idx - hy * 216;
        int hx  = rem / 12;
        int cc  = rem - hx * 12;
        int gy = by0 + hy - 1, gx = bx0 + hx - 1;
        half8 v = {(_Float16)0.f, (_Float16)0.f, (_Float16)0.f, (_Float16)0.f,
                   (_Float16)0.f, (_Float16)0.f, (_Float16)0.f, (_Float16)0.f};
        if (gy >= 0 && gy < HA && gx >= 0 && gx < HA)
            v = *(const half8*)(xH + (((size_t)b * HA + gy) * HA + gx) * 96 + cc * 8);
        *(half8*)&lds[(hy * 18 + hx) * 104 + cc * 8] = v;
    }

    float bv[3];
#pragma unroll
    for (int j = 0; j < 3; ++j) bv[j] = bias[(nh * 3 + j) * 16 + n_];

    __syncthreads();

    float4v acc[4][3];
#pragma unroll
    for (int r = 0; r < 4; ++r)
#pragma unroll
        for (int j = 0; j < 3; ++j) {
            float4v z = {0.f, 0.f, 0.f, 0.f};
            acc[r][j] = z;
        }

#pragma unroll 1
    for (int ky = 0; ky < 3; ++ky)
#pragma unroll 1
        for (int kx = 0; kx < 3; ++kx) {
            const int tap = ky * 3 + kx;
#pragma unroll
            for (int kc = 0; kc < 3; ++kc) {
                const int s = tap * 3 + kc;
                half8 bf[3];
#pragma unroll
                for (int j = 0; j < 3; ++j)
                    bf[j] = *(const half8*)(fragTabW +
                            ((size_t)(s * 6 + nh * 3 + j) * 64 + lane) * 8);
#pragma unroll
                for (int r = 0; r < 4; ++r) {
                    const int yr = yg * 4 + r;
                    half8 a = *(const half8*)&lds[((yr + ky) * 18 + (n_ + kx)) * 104
                                                  + kc * 32 + qd * 8];
#pragma unroll
                    for (int j = 0; j < 3; ++j)
                        acc[r][j] = __builtin_amdgcn_mfma_f32_16x16x32_f16(
                            a, bf[j], acc[r][j], 0, 0, 0);
                }
            }
        }

#pragma unroll
    for (int r = 0; r < 4; ++r) {
        const int gy = by0 + yg * 4 + r;
#pragma unroll
        for (int j = 0; j < 3; ++j) {
            const int ch = (nh * 3 + j) * 16 + n_;
#pragma unroll
            for (int reg = 0; reg < 4; ++reg) {
                const int gx = bx0 + qd * 4 + reg;
                yH[(((size_t)b * HA + gy) * HA + gx) * 96 + ch] =
                    (_Float16)fmaxf(acc[r][j][reg] + bv[j], 0.f);
            }
        }
    }
}

// ---- K4: sorted 4-corner gather + MLP ensemble via fp16 MFMA --------------
// Block: 256 threads = 64 rows = 16 queries x 4 corners; 1 M-tile per wave.
// LDS 25,344 B -> 5 blocks/CU under launch_bounds(256,5) (20 waves/CU).
__launch_bounds__(256, 5)
__global__ void decoder_mlp_mfma(const _Float16* __restrict__ asppH,
                                 const int* __restrict__ qidx,
                                 const float4v* __restrict__ qdata,
                                 const _Float16* __restrict__ fragTab,
                                 const float* __restrict__ mb0,
                                 const float* __restrict__ mb1,
                                 const float* __restrict__ mw2,
                                 const float* __restrict__ mb2,
                                 float* __restrict__ out) {
    __shared__ __align__(16) unsigned char smem[25344];
    _Float16* A   = (_Float16*)smem;              // 64*128*2 = 16384 B
    _Float16* Hb  = (_Float16*)(smem + 16384);    // 64*64*2  =  8192 B
    int*      pixL  = (int*)(smem + 24576);       // 256 B
    float*    areaL = (float*)(smem + 24832);     // 256 B
    float*    predL = (float*)(smem + 25088);     // 256 B

    const int tid  = threadIdx.x;
    const int lane = tid & 63;
    const int wv   = tid >> 6;
    const int n_   = lane & 15;
    const int qd   = lane >> 4;
    const int r    = (blockIdx.x & 7) * 2304 + (blockIdx.x >> 3);

    if (tid < 64) {
        const int lq = tid >> 2, k = tid & 3;
        const int sp = r * 16 + lq;
        const float4v d = qdata[sp];
        const int qq = qidx[sp];
        const int b  = qq / (HQ * HQ);
        const float cy = d[0], cx = d[1];
        const float rcy = d[2], rcx = d[3];

        const float LO = -1.0f + 1e-7f, HI = 1.0f - 1e-7f;
        const float RXY = 1.0f / (float)HA;
        const float vy = (k < 2) ? -1.f : 1.f;
        const float vx = (k & 1) ? 1.f : -1.f;

        float c0 = fminf(fmaxf((cy + vy * RXY) + 1e-7f, LO), HI);
        float c1 = fminf(fmaxf((cx + vx * RXY) + 1e-7f, LO), HI);
        int iy = (int)rintf(((c0 + 1.f) * (float)HA) * 0.5f - 0.5f);
        int ix = (int)rintf(((c1 + 1.f) * (float)HA) * 0.5f - 0.5f);
        iy = min(max(iy, 0), HA - 1);
        ix = min(max(ix, 0), HA - 1);

        const float cs0 = (((float)iy + 0.5f) / (float)HA) * 2.f - 1.f;
        const float cs1 = (((float)ix + 0.5f) / (float)HA) * 2.f - 1.f;
        const float r0 = (cy - cs0) * (float)HA;
        const float r1 = (cx - cs1) * (float)HA;

        pixL[tid]  = ((b * HA + iy) * HA + ix) * 96;
        areaL[tid] = fabsf(r0 * r1) + 1e-7f;

        const int row = tid;
        half8 e0;
        e0[0] = (_Float16)r0;  e0[1] = (_Float16)r1;
        e0[2] = (_Float16)cy;  e0[3] = (_Float16)cx;
        e0[4] = (_Float16)rcy; e0[5] = (_Float16)rcx;
        e0[6] = (_Float16)0.f; e0[7] = (_Float16)0.f;
        half8 z = {(_Float16)0.f, (_Float16)0.f, (_Float16)0.f, (_Float16)0.f,
                   (_Float16)0.f, (_Float16)0.f, (_Float16)0.f, (_Float16)0.f};
        *(half8*)&A[row * 128 + ((12 ^ (row & 15)) * 8)] = e0;
        *(half8*)&A[row * 128 + ((13 ^ (row & 15)) * 8)] = z;
        *(half8*)&A[row * 128 + ((14 ^ (row & 15)) * 8)] = z;
        *(half8*)&A[row * 128 + ((15 ^ (row & 15)) * 8)] = z;
    }

    half8 B0[16];
#pragma unroll
    for (int i = 0; i < 16; ++i)
        B0[i] = *(const half8*)(fragTab + ((size_t)i * 64 + lane) * 8);
    float mb0v[4], mb1v[4], w2v[4];
#pragma unroll
    for (int nt = 0; nt < 4; ++nt) {
        mb0v[nt] = mb0[nt * 16 + n_];
        mb1v[nt] = mb1[nt * 16 + n_];
        w2v[nt]  = mw2[nt * 16 + n_];
    }
    const float mb2s = mb2[0];

    __syncthreads();

    // gather: 16-lane groups, lanes 0..11 load one half8 each (192 B/row)
    {
        const int grp = tid >> 4;
        const int l   = tid & 15;
#pragma unroll 1
        for (int it = 0; it < 4; ++it) {
            const int row  = it * 16 + grp;
            const int base = pixL[row];
            if (l < 12) {
                half8 h = *(const half8*)(asppH + base + l * 8);
                *(half8*)&A[row * 128 + ((l ^ (row & 15)) * 8)] = h;
            }
        }
    }
    __syncthreads();

    // ---- one M-tile of 16 rows per wave ----
    {
        const int m0  = wv * 16;
        const int row = m0 + n_;

        float4v acc[4];
#pragma unroll
        for (int nt = 0; nt < 4; ++nt) {
            float4v t = {mb0v[nt], mb0v[nt], mb0v[nt], mb0v[nt]};
            acc[nt] = t;
        }
#pragma unroll
        for (int kc = 0; kc < 4; ++kc) {
            half8 a = *(const half8*)&A[row * 128 + (((kc * 4 + qd) ^ (row & 15)) * 8)];
#pragma unroll
            for (int nt = 0; nt < 4; ++nt)
                acc[nt] = __builtin_amdgcn_mfma_f32_16x16x32_f16(a, B0[kc * 4 + nt],
                                                                 acc[nt], 0, 0, 0);
        }
#pragma unroll
        for (int nt = 0; nt < 4; ++nt)
#pragma unroll
            for (int reg = 0; reg < 4; ++reg) {
                const int hr = m0 + qd * 4 + reg;
                const int n  = nt * 16 + n_;
                Hb[hr * 64 + (((n >> 3) ^ (hr & 7)) * 8) + (n & 7)] =
                    (_Float16)fmaxf(acc[nt][reg], 0.f);
            }
        __builtin_amdgcn_s_waitcnt(0);   // wave-local Hb write->read

        float4v acc1[4];
#pragma unroll
        for (int nt = 0; nt < 4; ++nt) {
            float4v t = {mb1v[nt], mb1v[nt], mb1v[nt], mb1v[nt]};
            acc1[nt] = t;
        }
#pragma unroll
        for (int kc = 0; kc < 2; ++kc) {
            half8 a1 = *(const half8*)&Hb[row * 64 + (((kc * 4 + qd) ^ (row & 7)) * 8)];
#pragma unroll
            for (int nt = 0; nt < 4; ++nt) {
                half8 b1 = *(const half8*)(fragTab +
                            ((size_t)(16 + kc * 4 + nt) * 64 + lane) * 8);
                acc1[nt] = __builtin_amdgcn_mfma_f32_16x16x32_f16(a1, b1,
                                                                  acc1[nt], 0, 0, 0);
            }
        }

        float p[4];
#pragma unroll
        for (int reg = 0; reg < 4; ++reg) {
            float s = 0.f;
#pragma unroll
            for (int nt = 0; nt < 4; ++nt)
                s = fmaf(fmaxf(acc1[nt][reg], 0.f), w2v[nt], s);
            s += __shfl_xor(s, 1, 64);
            s += __shfl_xor(s, 2, 64);
            s += __shfl_xor(s, 4, 64);
            s += __shfl_xor(s, 8, 64);
            p[reg] = s;
        }
        if (n_ == 0) {
            float4v pv = {p[0] + mb2s, p[1] + mb2s, p[2] + mb2s, p[3] + mb2s};
            *(float4v*)&predL[m0 + qd * 4] = pv;
        }
    }
    __syncthreads();

    if (tid < 16) {
        float4v pr = *(const float4v*)&predL[tid * 4];
        float4v ar = *(const float4v*)&areaL[tid * 4];
        float num = pr[0] * ar[3] + pr[1] * ar[2] + pr[2] * ar[1] + pr[3] * ar[0];
        float den = ar[0] + ar[1] + ar[2] + ar[3];
        out[qidx[r * 16 + tid]] = num / den;
    }
}

// ---------------------------------------------------------------------------
extern "C" void kernel_launch(void* const* d_in, const int* in_sizes, int n_in,
                              void* d_out, int out_size, void* d_ws, size_t ws_size,
                              hipStream_t stream) {
    (void)in_sizes; (void)n_in; (void)out_size; (void)ws_size;
    const float* feats2  = (const float*)d_in[0];
    const float* feats4  = (const float*)d_in[1];
    const float* feats32 = (const float*)d_in[2];
    const float* coords  = (const float*)d_in[3];
    const float* cells   = (const float*)d_in[4];
    const float* w2  = (const float*)d_in[5];
    const float* b2  = (const float*)d_in[6];
    const float* w4  = (const float*)d_in[7];
    const float* b4  = (const float*)d_in[8];
    const float* w32 = (const float*)d_in[9];
    const float* b32 = (const float*)d_in[10];
    const float* wf  = (const float*)d_in[11];
    const float* bf  = (const float*)d_in[12];
    const float* mw0 = (const float*)d_in[13];
    const float* mb0 = (const float*)d_in[14];
    const float* mw1 = (const float*)d_in[15];
    const float* mb1 = (const float*)d_in[16];
    const float* mw2 = (const float*)d_in[17];
    const float* mb2 = (const float*)d_in[18];

    float* ws = (float*)d_ws;
    float*    a4s   = ws;                          // 589824 f
    float*    a32s  = a4s + 589824;                // 36864 f
    _Float16* xcatH = (_Float16*)(a32s + 36864);   // 7,077,888 h
    _Float16* asppH = xcatH + 7077888;             // 7,077,888 h
    _Float16* fragTab  = asppH + 7077888;          // 12,288 h
    _Float16* fragTabW = fragTab + 12288;          // 82,944 h
    float4v*  qdata = (float4v*)(fragTabW + 82944);   // NQ * 16 B
    int*      qidx  = (int*)(qdata + NQ);             // NQ ints
    int*      cntT  = qidx + NQ;                      // NFLAT ints
    int*      scanEx = cntT + NFLAT;                  // NFLAT ints
    int*      partials = scanEx + NFLAT;              // 324 ints
    unsigned char* lrank = (unsigned char*)(partials + 324);  // NQ bytes
    float* out = (float*)d_out;

    prep_all<<<47, 256, 0, stream>>>(mw0, mw1, wf, fragTab, fragTabW);
    sort_count<<<NB, 256, 0, stream>>>(coords, cntT, lrank);
    scan_chunks<<<NFLAT / 1024, 1024, 0, stream>>>(cntT, scanEx, partials);
    scan_partials<<<1, 512, 0, stream>>>(partials);
    sort_scatter<<<NB, 256, 0, stream>>>(coords, cells, scanEx, partials,
                                         lrank, qidx, qdata);
    conv1x1_ab<<<612, 256, 0, stream>>>(feats4, w4, b4, feats32, w32, b32,
                                        a4s, a32s);
    build_xcat<<<dim3(2304, 3), 256, 0, stream>>>(feats2, w2, b2, a4s, a32s,
                                                  xcatH);
    conv3x3_mfma<<<dim3(12, 24, 2), 256, 0, stream>>>(xcatH, fragTabW, bf, asppH);
    decoder_mlp_mfma<<<18432, 256, 0, stream>>>(asppH, qidx, qdata, fragTab,
                                                mb0, mb1, mw2, mb2, out);
}

// Round 12
// 257.731 us; speedup vs baseline: 2.7038x; 1.0482x over previous
//
#include <hip/hip_runtime.h>
#include <math.h>

// ---------------------------------------------------------------------------
// Decoder_82764019794508: LIIF-style decoder.
// R12: barrier-free decoder. The MFMA A-fragment for lane(qd,n_) is a
// contiguous half8 at pix(row)+kc*32+qd*8 -> each lane gathers its own
// fragment directly from global; the 16KB LDS A-tile, the staging loop and
// both __syncthreads are removed. Corner math recomputed per-lane; combine
// done in-wave via shfl. LDS 25.3->8KB, launch_bounds(256,6) -> 24 waves/CU.
// All other kernels identical to R11. Numerics bit-identical.
// ---------------------------------------------------------------------------

#define HQ 384
#define HA 192
#define NQ (2 * HQ * HQ)   // 294912 queries
#define NB (NQ / 256)      // 1152 sort blocks
#define NBKT 288           // 2 batches x 12x12 tiles of 16x16 px
#define NFLAT (NBKT * NB)  // 331776 = 324 * 1024

typedef _Float16 half8  __attribute__((ext_vector_type(8)));
typedef _Float16 half4v __attribute__((ext_vector_type(4)));
typedef float    float4v __attribute__((ext_vector_type(4)));

// bucket id from query coords: corner k=0 (vy=vx=-1) pixel, 16x16 tiles
__device__ __forceinline__ int bucket_id(int q, float cy, float cx) {
    const float LO = -1.0f + 1e-7f, HI = 1.0f - 1e-7f;
    const float RXY = 1.0f / (float)HA;
    float c0 = fminf(fmaxf((cy - RXY) + 1e-7f, LO), HI);
    float c1 = fminf(fmaxf((cx - RXY) + 1e-7f, LO), HI);
    int iy = (int)rintf(((c0 + 1.f) * (float)HA) * 0.5f - 0.5f);
    int ix = (int)rintf(((c1 + 1.f) * (float)HA) * 0.5f - 0.5f);
    iy = min(max(iy, 0), HA - 1);
    ix = min(max(ix, 0), HA - 1);
    int b = q / (HQ * HQ);
    return b * 144 + (iy >> 4) * 12 + (ix >> 4);
}

// ---- K0: pack ALL weights into per-lane MFMA B-fragments ------------------
__global__ void prep_all(const float* __restrict__ mw0,
                         const float* __restrict__ mw1,
                         const float* __restrict__ wf,
                         _Float16* __restrict__ fragTab,
                         _Float16* __restrict__ fragTabW) {
    int t = blockIdx.x * 256 + threadIdx.x;
    if (t < 1536) {
        int f = t >> 6, L = t & 63;
        int n_ = L & 15, qd = L >> 4;
        _Float16 vals[8];
        if (f < 16) {
            int kc = f >> 2, nt = f & 3;
#pragma unroll
            for (int j = 0; j < 8; ++j) {
                int kk = kc * 32 + qd * 8 + j;
                vals[j] = (_Float16)((kk < 102) ? mw0[kk * 64 + nt * 16 + n_] : 0.f);
            }
        } else {
            int g = f - 16;
            int kc = g >> 2, nt = g & 3;
#pragma unroll
            for (int j = 0; j < 8; ++j) {
                int kk = kc * 32 + qd * 8 + j;
                vals[j] = (_Float16)mw1[kk * 64 + nt * 16 + n_];
            }
        }
#pragma unroll
        for (int j = 0; j < 8; ++j) fragTab[t * 8 + j] = vals[j];
    } else {
        int tw = t - 1536;
        if (tw >= 27 * 6 * 64) return;
        int s   = tw / 384;
        int rem = tw - s * 384;
        int nt  = rem >> 6;
        int L   = rem & 63;
        int n_  = L & 15, qd = L >> 4;
        int tap = s / 3, kc = s - tap * 3;
#pragma unroll
        for (int j = 0; j < 8; ++j) {
            int kch = kc * 32 + qd * 8 + j;
            fragTabW[tw * 8 + j] = (_Float16)wf[(tap * 96 + kch) * 96 + nt * 16 + n_];
        }
    }
}

// ---- K_s1: per-block LDS histogram + local rank; counts stored transposed -
__global__ void sort_count(const float* __restrict__ coords,
                           int* __restrict__ cntT,
                           unsigned char* __restrict__ lrank) {
    __shared__ int lh[NBKT];
    const int tid = threadIdx.x;
    for (int i = tid; i < NBKT; i += 256) lh[i] = 0;
    __syncthreads();
    const int q = blockIdx.x * 256 + tid;
    float cy = coords[(size_t)q * 2 + 0];
    float cx = coords[(size_t)q * 2 + 1];
    int r = atomicAdd(&lh[bucket_id(q, cy, cx)], 1);   // LDS atomic only
    lrank[q] = (unsigned char)r;
    __syncthreads();
    for (int i = tid; i < NBKT; i += 256)
        cntT[i * NB + blockIdx.x] = lh[i];             // bucket-major layout
}

// ---- K_s2a: per-1024-chunk exclusive scan (coalesced, LDS Hillis-Steele) --
__global__ void scan_chunks(const int* __restrict__ cntT,
                            int* __restrict__ scanEx,
                            int* __restrict__ partials) {
    __shared__ int s[1024];
    const int t = threadIdx.x;
    const int gi = blockIdx.x * 1024 + t;
    int v = cntT[gi];
    s[t] = v;
    __syncthreads();
    for (int off = 1; off < 1024; off <<= 1) {
        int x = (t >= off) ? s[t - off] : 0;
        __syncthreads();
        s[t] += x;
        __syncthreads();
    }
    scanEx[gi] = s[t] - v;                 // exclusive within chunk
    if (t == 1023) partials[blockIdx.x] = s[t];
}

// ---- K_s2b: exclusive scan of 324 chunk totals ----------------------------
__global__ void scan_partials(int* __restrict__ partials) {
    __shared__ int s[512];
    const int t = threadIdx.x;
    int v = (t < 324) ? partials[t] : 0;
    s[t] = v;
    __syncthreads();
    for (int off = 1; off < 512; off <<= 1) {
        int x = (t >= off) ? s[t - off] : 0;
        __syncthreads();
        s[t] += x;
        __syncthreads();
    }
    if (t < 324) partials[t] = s[t] - v;   // in-place exclusive
}

// ---- K_s3: scatter query indices + packed per-query data (no atomics) -----
__global__ void sort_scatter(const float* __restrict__ coords,
                             const float* __restrict__ cells,
                             const int* __restrict__ scanEx,
                             const int* __restrict__ partials,
                             const unsigned char* __restrict__ lrank,
                             int* __restrict__ qidx,
                             float4v* __restrict__ qdata) {
    const int q = blockIdx.x * 256 + threadIdx.x;
    float cy = coords[(size_t)q * 2 + 0];
    float cx = coords[(size_t)q * 2 + 1];
    int bkt = bucket_id(q, cy, cx);
    int li  = bkt * NB + blockIdx.x;
    int pos = partials[li >> 10] + scanEx[li] + (int)lrank[q];
    qidx[pos] = q;
    float4v d = {cy, cx,
                 cells[(size_t)q * 2 + 0] * (float)HA,
                 cells[(size_t)q * 2 + 1] * (float)HA};
    qdata[pos] = d;
}

// ---- K1: fused 1x1 convs, 4 output channels per thread --------------------
__global__ void conv1x1_ab(const float* __restrict__ feats4,
                           const float* __restrict__ w4,
                           const float* __restrict__ b4,
                           const float* __restrict__ feats32,
                           const float* __restrict__ w32,
                           const float* __restrict__ b32,
                           float* __restrict__ a4s,
                           float* __restrict__ a32s) {
    int blk = blockIdx.x;
    if (blk < 576) {                       // 18432 px * 8 thr
        int t = blk * 256 + threadIdx.x;
        int p = t >> 3, cg = t & 7;
        const float4v* xr = (const float4v*)(feats4 + (size_t)p * 96);
        float4v acc = *(const float4v*)(b4 + cg * 4);
#pragma unroll
        for (int i4 = 0; i4 < 24; ++i4) {
            float4v xv = xr[i4];
            const float* wr = w4 + (i4 * 4) * 32 + cg * 4;
#pragma unroll
            for (int j = 0; j < 4; ++j) {
                float4v wv = *(const float4v*)(wr + j * 32);
                acc[0] = fmaf(xv[j], wv[0], acc[0]);
                acc[1] = fmaf(xv[j], wv[1], acc[1]);
                acc[2] = fmaf(xv[j], wv[2], acc[2]);
                acc[3] = fmaf(xv[j], wv[3], acc[3]);
            }
        }
        float4v o = {fmaxf(acc[0], 0.f), fmaxf(acc[1], 0.f),
                     fmaxf(acc[2], 0.f), fmaxf(acc[3], 0.f)};
        *(float4v*)(a4s + (size_t)p * 32 + cg * 4) = o;
    } else {                               // 1152 px * 8 thr = 36 blocks
        int t = (blk - 576) * 256 + threadIdx.x;
        if (t >= 1152 * 8) return;
        int p = t >> 3, cg = t & 7;
        const float4v* xr = (const float4v*)(feats32 + (size_t)p * 160);
        float4v acc = *(const float4v*)(b32 + cg * 4);
#pragma unroll
        for (int i4 = 0; i4 < 40; ++i4) {
            float4v xv = xr[i4];
            const float* wr = w32 + (i4 * 4) * 32 + cg * 4;
#pragma unroll
            for (int j = 0; j < 4; ++j) {
                float4v wv = *(const float4v*)(wr + j * 32);
                acc[0] = fmaf(xv[j], wv[0], acc[0]);
                acc[1] = fmaf(xv[j], wv[1], acc[1]);
                acc[2] = fmaf(xv[j], wv[2], acc[2]);
                acc[3] = fmaf(xv[j], wv[3], acc[3]);
            }
        }
        float4v o = {fmaxf(acc[0], 0.f), fmaxf(acc[1], 0.f),
                     fmaxf(acc[2], 0.f), fmaxf(acc[3], 0.f)};
        *(float4v*)(a32s + (size_t)p * 32 + cg * 4) = o;
    }
}

// ---- K2: build xcat (fp16), 4 channels per thread, 3 slices ---------------
__global__ void build_xcat(const float* __restrict__ feats2,
                           const float* __restrict__ w2,
                           const float* __restrict__ b2,
                           const float* __restrict__ a4s,
                           const float* __restrict__ a32s,
                           _Float16* __restrict__ xcatH) {
    const int z = blockIdx.y;
    int t = blockIdx.x * 256 + threadIdx.x;     // 2304 blocks: 73728 px * 8
    int p = t >> 3, cg = t & 7;

    if (z == 0) {
        const float4v* xr = (const float4v*)(feats2 + (size_t)p * 64);
        float4v acc = *(const float4v*)(b2 + cg * 4);
#pragma unroll
        for (int i4 = 0; i4 < 16; ++i4) {
            float4v xv = xr[i4];
            const float* wr = w2 + (i4 * 4) * 32 + cg * 4;
#pragma unroll
            for (int j = 0; j < 4; ++j) {
                float4v wv = *(const float4v*)(wr + j * 32);
                acc[0] = fmaf(xv[j], wv[0], acc[0]);
                acc[1] = fmaf(xv[j], wv[1], acc[1]);
                acc[2] = fmaf(xv[j], wv[2], acc[2]);
                acc[3] = fmaf(xv[j], wv[3], acc[3]);
            }
        }
        half4v h;
        h[0] = (_Float16)fmaxf(acc[0], 0.f);
        h[1] = (_Float16)fmaxf(acc[1], 0.f);
        h[2] = (_Float16)fmaxf(acc[2], 0.f);
        h[3] = (_Float16)fmaxf(acc[3], 0.f);
        *(half4v*)(xcatH + (size_t)p * 96 + cg * 4) = h;
        return;
    }

    const float* src = (z == 1) ? a4s : a32s;
    const int   S    = (z == 1) ? 96 : 24;
    const float inv  = (z == 1) ? 0.5f : 0.125f;
    const int   coff = (z == 1) ? 32 : 64;

    int x = p % HA;
    int r = p / HA;
    int y = r % HA;
    int b = r / HA;

    float u = ((float)y + 0.5f) * inv - 0.5f;
    float v = ((float)x + 0.5f) * inv - 0.5f;
    float fu = floorf(u), fv = floorf(v);
    float wu = u - fu, wv = v - fv;
    int y0 = (int)fu, x0 = (int)fv;
    int y1 = min(y0 + 1, S - 1);
    int x1 = min(x0 + 1, S - 1);
    y0 = max(y0, 0);
    x0 = max(x0, 0);

    const float* sb = src + (size_t)b * S * S * 32 + cg * 4;
    float4v v00 = *(const float4v*)(sb + (y0 * S + x0) * 32);
    float4v v01 = *(const float4v*)(sb + (y0 * S + x1) * 32);
    float4v v10 = *(const float4v*)(sb + (y1 * S + x0) * 32);
    float4v v11 = *(const float4v*)(sb + (y1 * S + x1) * 32);
    half4v h;
#pragma unroll
    for (int j = 0; j < 4; ++j) {
        float t0 = v00[j] * (1.f - wu) + v10[j] * wu;
        float t1 = v01[j] * (1.f - wu) + v11[j] * wu;
        h[j] = (_Float16)(t0 * (1.f - wv) + t1 * wv);
    }
    *(half4v*)(xcatH + (size_t)p * 96 + coff + cg * 4) = h;
}

// ---- K3: 3x3 conv 96->96 + bias + ReLU via fp16 MFMA, fp16 in/out ---------
__launch_bounds__(256, 4)
__global__ void conv3x3_mfma(const _Float16* __restrict__ xH,
                             const _Float16* __restrict__ fragTabW,
                             const float* __restrict__ bias,
                             _Float16* __restrict__ yH) {
    __shared__ _Float16 lds[10 * 18 * 104];
    const int tid = threadIdx.x;
    const int lane = tid & 63;
    const int wv   = tid >> 6;
    const int n_   = lane & 15;
    const int qd   = lane >> 4;
    const int nh   = wv & 1;
    const int yg   = wv >> 1;
    const int bx0  = blockIdx.x * 16;
    const int by0  = blockIdx.y * 8;
    const int b    = blockIdx.z;

    for (int idx = tid; idx < 2160; idx += 256) {
        int hy  = idx / 216;
        int rem = idx - hy * 216;
        int hx  = rem / 12;
        int cc  = rem - hx * 12;
        int gy = by0 + hy - 1, gx = bx0 + hx - 1;
        half8 v = {(_Float16)0.f, (_Float16)0.f, (_Float16)0.f, (_Float16)0.f,
                   (_Float16)0.f, (_Float16)0.f, (_Float16)0.f, (_Float16)0.f};
        if (gy >= 0 && gy < HA && gx >= 0 && gx < HA)
            v = *(const half8*)(xH + (((size_t)b * HA + gy) * HA + gx) * 96 + cc * 8);
        *(half8*)&lds[(hy * 18 + hx) * 104 + cc * 8] = v;
    }

    float bv[3];
#pragma unroll
    for (int j = 0; j < 3; ++j) bv[j] = bias[(nh * 3 + j) * 16 + n_];

    __syncthreads();

    float4v acc[4][3];
#pragma unroll
    for (int r = 0; r < 4; ++r)
#pragma unroll
        for (int j = 0; j < 3; ++j) {
            float4v z = {0.f, 0.f, 0.f, 0.f};
            acc[r][j] = z;
        }

#pragma unroll 1
    for (int ky = 0; ky < 3; ++ky)
#pragma unroll 1
        for (int kx = 0; kx < 3; ++kx) {
            const int tap = ky * 3 + kx;
#pragma unroll
            for (int kc = 0; kc < 3; ++kc) {
                const int s = tap * 3 + kc;
                half8 bf[3];
#pragma unroll
                for (int j = 0; j < 3; ++j)
                    bf[j] = *(const half8*)(fragTabW +
                            ((size_t)(s * 6 + nh * 3 + j) * 64 + lane) * 8);
#pragma unroll
                for (int r = 0; r < 4; ++r) {
                    const int yr = yg * 4 + r;
                    half8 a = *(const half8*)&lds[((yr + ky) * 18 + (n_ + kx)) * 104
                                                  + kc * 32 + qd * 8];
#pragma unroll
                    for (int j = 0; j < 3; ++j)
                        acc[r][j] = __builtin_amdgcn_mfma_f32_16x16x32_f16(
                            a, bf[j], acc[r][j], 0, 0, 0);
                }
            }
        }

#pragma unroll
    for (int r = 0; r < 4; ++r) {
        const int gy = by0 + yg * 4 + r;
#pragma unroll
        for (int j = 0; j < 3; ++j) {
            const int ch = (nh * 3 + j) * 16 + n_;
#pragma unroll
            for (int reg = 0; reg < 4; ++reg) {
                const int gx = bx0 + qd * 4 + reg;
                yH[(((size_t)b * HA + gy) * HA + gx) * 96 + ch] =
                    (_Float16)fmaxf(acc[r][j][reg] + bv[j], 0.f);
            }
        }
    }
}

// ---- K4: sorted gather + MLP, barrier-free --------------------------------
// Wave = 16 rows = 4 queries x 4 corners. Each lane (qd,n_) owns row n_ and
// loads its own A fragments directly (pix + kc*32 + qd*8). Only LDS: Hb
// (layer0->layer1 transpose, wave-local slice). No __syncthreads anywhere.
__launch_bounds__(256, 6)
__global__ void decoder_mlp_mfma(const _Float16* __restrict__ asppH,
                                 const int* __restrict__ qidx,
                                 const float4v* __restrict__ qdata,
                                 const _Float16* __restrict__ fragTab,
                                 const float* __restrict__ mb0,
                                 const float* __restrict__ mb1,
                                 const float* __restrict__ mw2,
                                 const float* __restrict__ mb2,
                                 float* __restrict__ out) {
    __shared__ _Float16 Hb[64 * 64];   // 8 KB, wave-local 16x64 slices

    const int tid  = threadIdx.x;
    const int lane = tid & 63;
    const int wv   = tid >> 6;
    const int n_   = lane & 15;
    const int qd   = lane >> 4;
    const int r    = (blockIdx.x & 7) * 2304 + (blockIdx.x >> 3);
    const int m0   = wv * 16;

    // ---- per-lane corner data for row m0+n_ (query m0/4 + n_/4, corner n_&3)
    const int sp = r * 16 + (m0 >> 2) + (n_ >> 2);
    const float4v d = qdata[sp];
    const int   qq = qidx[sp];
    const int   b  = qq / (HQ * HQ);
    const float cy = d[0], cx = d[1], rcy = d[2], rcx = d[3];
    const int   k  = n_ & 3;

    const float LO = -1.0f + 1e-7f, HI = 1.0f - 1e-7f;
    const float RXY = 1.0f / (float)HA;
    const float vy = (k < 2) ? -1.f : 1.f;
    const float vx = (k & 1) ? 1.f : -1.f;

    float c0 = fminf(fmaxf((cy + vy * RXY) + 1e-7f, LO), HI);
    float c1 = fminf(fmaxf((cx + vx * RXY) + 1e-7f, LO), HI);
    int iy = (int)rintf(((c0 + 1.f) * (float)HA) * 0.5f - 0.5f);
    int ix = (int)rintf(((c1 + 1.f) * (float)HA) * 0.5f - 0.5f);
    iy = min(max(iy, 0), HA - 1);
    ix = min(max(ix, 0), HA - 1);

    const float cs0 = (((float)iy + 0.5f) / (float)HA) * 2.f - 1.f;
    const float cs1 = (((float)ix + 0.5f) / (float)HA) * 2.f - 1.f;
    const float r0 = (cy - cs0) * (float)HA;
    const float r1 = (cx - cs1) * (float)HA;
    const float area = fabsf(r0 * r1) + 1e-7f;
    const int   pix = ((b * HA + iy) * HA + ix) * 96;

    // ---- A fragments: kc=0..2 direct gather; kc=3 = extras in-register ----
    half8 A_[4];
    A_[0] = *(const half8*)(asppH + pix + 0 * 32 + qd * 8);
    A_[1] = *(const half8*)(asppH + pix + 1 * 32 + qd * 8);
    A_[2] = *(const half8*)(asppH + pix + 2 * 32 + qd * 8);
    {
        half8 e = {(_Float16)0.f, (_Float16)0.f, (_Float16)0.f, (_Float16)0.f,
                   (_Float16)0.f, (_Float16)0.f, (_Float16)0.f, (_Float16)0.f};
        if (qd == 0) {
            e[0] = (_Float16)r0;  e[1] = (_Float16)r1;
            e[2] = (_Float16)cy;  e[3] = (_Float16)cx;
            e[4] = (_Float16)rcy; e[5] = (_Float16)rcx;
        }
        A_[3] = e;
    }

    // ---- biases / layer2 weights (col = n_ per C layout) ----
    float mb0v[4], mb1v[4], w2v[4];
#pragma unroll
    for (int nt = 0; nt < 4; ++nt) {
        mb0v[nt] = mb0[nt * 16 + n_];
        mb1v[nt] = mb1[nt * 16 + n_];
        w2v[nt]  = mw2[nt * 16 + n_];
    }
    const float mb2s = mb2[0];

    // ---- layer0: 16 MFMAs ----
    float4v acc[4];
#pragma unroll
    for (int nt = 0; nt < 4; ++nt) {
        float4v t = {mb0v[nt], mb0v[nt], mb0v[nt], mb0v[nt]};
        acc[nt] = t;
    }
#pragma unroll
    for (int kc = 0; kc < 4; ++kc)
#pragma unroll
        for (int nt = 0; nt < 4; ++nt) {
            half8 b0 = *(const half8*)(fragTab +
                        ((size_t)(kc * 4 + nt) * 64 + lane) * 8);
            acc[nt] = __builtin_amdgcn_mfma_f32_16x16x32_f16(A_[kc], b0,
                                                             acc[nt], 0, 0, 0);
        }

    // ---- relu -> Hb (wave-local swizzled slice) ----
#pragma unroll
    for (int nt = 0; nt < 4; ++nt)
#pragma unroll
        for (int reg = 0; reg < 4; ++reg) {
            const int hr = m0 + qd * 4 + reg;
            const int nn = nt * 16 + n_;
            Hb[hr * 64 + (((nn >> 3) ^ (hr & 7)) * 8) + (nn & 7)] =
                (_Float16)fmaxf(acc[nt][reg], 0.f);
        }
    __builtin_amdgcn_s_waitcnt(0);   // drain LDS writes (wave-local dep)

    // ---- layer1: 8 MFMAs ----
    const int row = m0 + n_;
    float4v acc1[4];
#pragma unroll
    for (int nt = 0; nt < 4; ++nt) {
        float4v t = {mb1v[nt], mb1v[nt], mb1v[nt], mb1v[nt]};
        acc1[nt] = t;
    }
#pragma unroll
    for (int kc = 0; kc < 2; ++kc) {
        half8 a1 = *(const half8*)&Hb[row * 64 + (((kc * 4 + qd) ^ (row & 7)) * 8)];
#pragma unroll
        for (int nt = 0; nt < 4; ++nt) {
            half8 b1 = *(const half8*)(fragTab +
                        ((size_t)(16 + kc * 4 + nt) * 64 + lane) * 8);
            acc1[nt] = __builtin_amdgcn_mfma_f32_16x16x32_f16(a1, b1,
                                                              acc1[nt], 0, 0, 0);
        }
    }

    // ---- layer2 + in-wave combine ----
    float p[4];
#pragma unroll
    for (int reg = 0; reg < 4; ++reg) {
        float s = 0.f;
#pragma unroll
        for (int nt = 0; nt < 4; ++nt)
            s = fmaf(fmaxf(acc1[nt][reg], 0.f), w2v[nt], s);
        s += __shfl_xor(s, 1, 64);
        s += __shfl_xor(s, 2, 64);
        s += __shfl_xor(s, 4, 64);
        s += __shfl_xor(s, 8, 64);
        p[reg] = s + mb2s;      // pred of row m0 + qd*4 + reg
    }

    // areas of rows qd*4+k live in lanes (qd'=0, n_=qd*4+k)
    float a0s = __shfl(area, qd * 4 + 0, 64);
    float a1s = __shfl(area, qd * 4 + 1, 64);
    float a2s = __shfl(area, qd * 4 + 2, 64);
    float a3s = __shfl(area, qd * 4 + 3, 64);
    int   oq  = __shfl(qq,   qd * 4, 64);   // qidx of query m0/4 + qd

    if (n_ == 0) {
        float num = p[0] * a3s + p[1] * a2s + p[2] * a1s + p[3] * a0s;
        float den = a0s + a1s + a2s + a3s;
        out[oq] = num / den;
    }
}

// ---------------------------------------------------------------------------
extern "C" void kernel_launch(void* const* d_in, const int* in_sizes, int n_in,
                              void* d_out, int out_size, void* d_ws, size_t ws_size,
                              hipStream_t stream) {
    (void)in_sizes; (void)n_in; (void)out_size; (void)ws_size;
    const float* feats2  = (const float*)d_in[0];
    const float* feats4  = (const float*)d_in[1];
    const float* feats32 = (const float*)d_in[2];
    const float* coords  = (const float*)d_in[3];
    const float* cells   = (const float*)d_in[4];
    const float* w2  = (const float*)d_in[5];
    const float* b2  = (const float*)d_in[6];
    const float* w4  = (const float*)d_in[7];
    const float* b4  = (const float*)d_in[8];
    const float* w32 = (const float*)d_in[9];
    const float* b32 = (const float*)d_in[10];
    const float* wf  = (const float*)d_in[11];
    const float* bf  = (const float*)d_in[12];
    const float* mw0 = (const float*)d_in[13];
    const float* mb0 = (const float*)d_in[14];
    const float* mw1 = (const float*)d_in[15];
    const float* mb1 = (const float*)d_in[16];
    const float* mw2 = (const float*)d_in[17];
    const float* mb2 = (const float*)d_in[18];

    float* ws = (float*)d_ws;
    float*    a4s   = ws;                          // 589824 f
    float*    a32s  = a4s + 589824;                // 36864 f
    _Float16* xcatH = (_Float16*)(a32s + 36864);   // 7,077,888 h
    _Float16* asppH = xcatH + 7077888;             // 7,077,888 h
    _Float16* fragTab  = asppH + 7077888;          // 12,288 h
    _Float16* fragTabW = fragTab + 12288;          // 82,944 h
    float4v*  qdata = (float4v*)(fragTabW + 82944);   // NQ * 16 B
    int*      qidx  = (int*)(qdata + NQ);             // NQ ints
    int*      cntT  = qidx + NQ;                      // NFLAT ints
    int*      scanEx = cntT + NFLAT;                  // NFLAT ints
    int*      partials = scanEx + NFLAT;              // 324 ints
    unsigned char* lrank = (unsigned char*)(partials + 324);  // NQ bytes
    float* out = (float*)d_out;

    prep_all<<<47, 256, 0, stream>>>(mw0, mw1, wf, fragTab, fragTabW);
    sort_count<<<NB, 256, 0, stream>>>(coords, cntT, lrank);
    scan_chunks<<<NFLAT / 1024, 1024, 0, stream>>>(cntT, scanEx, partials);
    scan_partials<<<1, 512, 0, stream>>>(partials);
    sort_scatter<<<NB, 256, 0, stream>>>(coords, cells, scanEx, partials,
                                         lrank, qidx, qdata);
    conv1x1_ab<<<612, 256, 0, stream>>>(feats4, w4, b4, feats32, w32, b32,
                                        a4s, a32s);
    build_xcat<<<dim3(2304, 3), 256, 0, stream>>>(feats2, w2, b2, a4s, a32s,
                                                  xcatH);
    conv3x3_mfma<<<dim3(12, 24, 2), 256, 0, stream>>>(xcatH, fragTabW, bf, asppH);
    decoder_mlp_mfma<<<18432, 256, 0, stream>>>(asppH, qidx, qdata, fragTab,
                                                mb0, mb1, mw2, mb2, out);
}

// Round 13
// 254.810 us; speedup vs baseline: 2.7348x; 1.0115x over previous
//
#include <hip/hip_runtime.h>
#include <math.h>

// ---------------------------------------------------------------------------
// Decoder_82764019794508: LIIF-style decoder.
// R13: (1) decoder launch_bounds(256,8): VGPR=32/LDS=8KB allow 8 blocks/CU
// (32 waves = HW max); R12's cap of 6 was the only occupancy limiter.
// (2) sort chain on 1024-thread blocks: NB 1152->288, NFLAT 331776->82944
// (scan traffic 2.6->0.66 MB), lrank u16. Within-bucket order changes only;
// per-query numerics bit-identical (corners stay co-wave, out[qidx] per query).
// ---------------------------------------------------------------------------

#define HQ 384
#define HA 192
#define NQ (2 * HQ * HQ)   // 294912 queries
#define NBS (NQ / 1024)    // 288 sort blocks (1024 threads each)
#define NBKT 288           // 2 batches x 12x12 tiles of 16x16 px
#define NFLAT (NBKT * NBS) // 82944 = 81 * 1024

typedef _Float16 half8  __attribute__((ext_vector_type(8)));
typedef _Float16 half4v __attribute__((ext_vector_type(4)));
typedef float    float4v __attribute__((ext_vector_type(4)));

// bucket id from query coords: corner k=0 (vy=vx=-1) pixel, 16x16 tiles
__device__ __forceinline__ int bucket_id(int q, float cy, float cx) {
    const float LO = -1.0f + 1e-7f, HI = 1.0f - 1e-7f;
    const float RXY = 1.0f / (float)HA;
    float c0 = fminf(fmaxf((cy - RXY) + 1e-7f, LO), HI);
    float c1 = fminf(fmaxf((cx - RXY) + 1e-7f, LO), HI);
    int iy = (int)rintf(((c0 + 1.f) * (float)HA) * 0.5f - 0.5f);
    int ix = (int)rintf(((c1 + 1.f) * (float)HA) * 0.5f - 0.5f);
    iy = min(max(iy, 0), HA - 1);
    ix = min(max(ix, 0), HA - 1);
    int b = q / (HQ * HQ);
    return b * 144 + (iy >> 4) * 12 + (ix >> 4);
}

// ---- K0: pack ALL weights into per-lane MFMA B-fragments ------------------
__global__ void prep_all(const float* __restrict__ mw0,
                         const float* __restrict__ mw1,
                         const float* __restrict__ wf,
                         _Float16* __restrict__ fragTab,
                         _Float16* __restrict__ fragTabW) {
    int t = blockIdx.x * 256 + threadIdx.x;
    if (t < 1536) {
        int f = t >> 6, L = t & 63;
        int n_ = L & 15, qd = L >> 4;
        _Float16 vals[8];
        if (f < 16) {
            int kc = f >> 2, nt = f & 3;
#pragma unroll
            for (int j = 0; j < 8; ++j) {
                int kk = kc * 32 + qd * 8 + j;
                vals[j] = (_Float16)((kk < 102) ? mw0[kk * 64 + nt * 16 + n_] : 0.f);
            }
        } else {
            int g = f - 16;
            int kc = g >> 2, nt = g & 3;
#pragma unroll
            for (int j = 0; j < 8; ++j) {
                int kk = kc * 32 + qd * 8 + j;
                vals[j] = (_Float16)mw1[kk * 64 + nt * 16 + n_];
            }
        }
#pragma unroll
        for (int j = 0; j < 8; ++j) fragTab[t * 8 + j] = vals[j];
    } else {
        int tw = t - 1536;
        if (tw >= 27 * 6 * 64) return;
        int s   = tw / 384;
        int rem = tw - s * 384;
        int nt  = rem >> 6;
        int L   = rem & 63;
        int n_  = L & 15, qd = L >> 4;
        int tap = s / 3, kc = s - tap * 3;
#pragma unroll
        for (int j = 0; j < 8; ++j) {
            int kch = kc * 32 + qd * 8 + j;
            fragTabW[tw * 8 + j] = (_Float16)wf[(tap * 96 + kch) * 96 + nt * 16 + n_];
        }
    }
}

// ---- K_s1: per-block LDS histogram + local rank (1024-thread blocks) ------
__global__ void sort_count(const float* __restrict__ coords,
                           int* __restrict__ cntT,
                           unsigned short* __restrict__ lrank) {
    __shared__ int lh[NBKT];
    const int tid = threadIdx.x;
    if (tid < NBKT) lh[tid] = 0;
    __syncthreads();
    const int q = blockIdx.x * 1024 + tid;
    float cy = coords[(size_t)q * 2 + 0];
    float cx = coords[(size_t)q * 2 + 1];
    int r = atomicAdd(&lh[bucket_id(q, cy, cx)], 1);   // LDS atomic only
    lrank[q] = (unsigned short)r;
    __syncthreads();
    if (tid < NBKT)
        cntT[tid * NBS + blockIdx.x] = lh[tid];        // bucket-major layout
}

// ---- K_s2a: per-1024-chunk exclusive scan (coalesced, LDS Hillis-Steele) --
__global__ void scan_chunks(const int* __restrict__ cntT,
                            int* __restrict__ scanEx,
                            int* __restrict__ partials) {
    __shared__ int s[1024];
    const int t = threadIdx.x;
    const int gi = blockIdx.x * 1024 + t;
    int v = cntT[gi];
    s[t] = v;
    __syncthreads();
    for (int off = 1; off < 1024; off <<= 1) {
        int x = (t >= off) ? s[t - off] : 0;
        __syncthreads();
        s[t] += x;
        __syncthreads();
    }
    scanEx[gi] = s[t] - v;                 // exclusive within chunk
    if (t == 1023) partials[blockIdx.x] = s[t];
}

// ---- K_s2b: exclusive scan of 81 chunk totals -----------------------------
__global__ void scan_partials(int* __restrict__ partials) {
    __shared__ int s[128];
    const int t = threadIdx.x;
    int v = (t < NFLAT / 1024) ? partials[t] : 0;
    s[t] = v;
    __syncthreads();
    for (int off = 1; off < 128; off <<= 1) {
        int x = (t >= off) ? s[t - off] : 0;
        __syncthreads();
        s[t] += x;
        __syncthreads();
    }
    if (t < NFLAT / 1024) partials[t] = s[t] - v;   // in-place exclusive
}

// ---- K_s3: scatter query indices + packed per-query data (no atomics) -----
__global__ void sort_scatter(const float* __restrict__ coords,
                             const float* __restrict__ cells,
                             const int* __restrict__ scanEx,
                             const int* __restrict__ partials,
                             const unsigned short* __restrict__ lrank,
                             int* __restrict__ qidx,
                             float4v* __restrict__ qdata) {
    const int q = blockIdx.x * 1024 + threadIdx.x;
    float cy = coords[(size_t)q * 2 + 0];
    float cx = coords[(size_t)q * 2 + 1];
    int bkt = bucket_id(q, cy, cx);
    int li  = bkt * NBS + blockIdx.x;
    int pos = partials[li >> 10] + scanEx[li] + (int)lrank[q];
    qidx[pos] = q;
    float4v d = {cy, cx,
                 cells[(size_t)q * 2 + 0] * (float)HA,
                 cells[(size_t)q * 2 + 1] * (float)HA};
    qdata[pos] = d;
}

// ---- K1: fused 1x1 convs, 4 output channels per thread --------------------
__global__ void conv1x1_ab(const float* __restrict__ feats4,
                           const float* __restrict__ w4,
                           const float* __restrict__ b4,
                           const float* __restrict__ feats32,
                           const float* __restrict__ w32,
                           const float* __restrict__ b32,
                           float* __restrict__ a4s,
                           float* __restrict__ a32s) {
    int blk = blockIdx.x;
    if (blk < 576) {                       // 18432 px * 8 thr
        int t = blk * 256 + threadIdx.x;
        int p = t >> 3, cg = t & 7;
        const float4v* xr = (const float4v*)(feats4 + (size_t)p * 96);
        float4v acc = *(const float4v*)(b4 + cg * 4);
#pragma unroll
        for (int i4 = 0; i4 < 24; ++i4) {
            float4v xv = xr[i4];
            const float* wr = w4 + (i4 * 4) * 32 + cg * 4;
#pragma unroll
            for (int j = 0; j < 4; ++j) {
                float4v wv = *(const float4v*)(wr + j * 32);
                acc[0] = fmaf(xv[j], wv[0], acc[0]);
                acc[1] = fmaf(xv[j], wv[1], acc[1]);
                acc[2] = fmaf(xv[j], wv[2], acc[2]);
                acc[3] = fmaf(xv[j], wv[3], acc[3]);
            }
        }
        float4v o = {fmaxf(acc[0], 0.f), fmaxf(acc[1], 0.f),
                     fmaxf(acc[2], 0.f), fmaxf(acc[3], 0.f)};
        *(float4v*)(a4s + (size_t)p * 32 + cg * 4) = o;
    } else {                               // 1152 px * 8 thr = 36 blocks
        int t = (blk - 576) * 256 + threadIdx.x;
        if (t >= 1152 * 8) return;
        int p = t >> 3, cg = t & 7;
        const float4v* xr = (const float4v*)(feats32 + (size_t)p * 160);
        float4v acc = *(const float4v*)(b32 + cg * 4);
#pragma unroll
        for (int i4 = 0; i4 < 40; ++i4) {
            float4v xv = xr[i4];
            const float* wr = w32 + (i4 * 4) * 32 + cg * 4;
#pragma unroll
            for (int j = 0; j < 4; ++j) {
                float4v wv = *(const float4v*)(wr + j * 32);
                acc[0] = fmaf(xv[j], wv[0], acc[0]);
                acc[1] = fmaf(xv[j], wv[1], acc[1]);
                acc[2] = fmaf(xv[j], wv[2], acc[2]);
                acc[3] = fmaf(xv[j], wv[3], acc[3]);
            }
        }
        float4v o = {fmaxf(acc[0], 0.f), fmaxf(acc[1], 0.f),
                     fmaxf(acc[2], 0.f), fmaxf(acc[3], 0.f)};
        *(float4v*)(a32s + (size_t)p * 32 + cg * 4) = o;
    }
}

// ---- K2: build xcat (fp16), 4 channels per thread, 3 slices ---------------
__global__ void build_xcat(const float* __restrict__ feats2,
                           const float* __restrict__ w2,
                           const float* __restrict__ b2,
                           const float* __restrict__ a4s,
                           const float* __restrict__ a32s,
                           _Float16* __restrict__ xcatH) {
    const int z = blockIdx.y;
    int t = blockIdx.x * 256 + threadIdx.x;     // 2304 blocks: 73728 px * 8
    int p = t >> 3, cg = t & 7;

    if (z == 0) {
        const float4v* xr = (const float4v*)(feats2 + (size_t)p * 64);
        float4v acc = *(const float4v*)(b2 + cg * 4);
#pragma unroll
        for (int i4 = 0; i4 < 16; ++i4) {
            float4v xv = xr[i4];
            const float* wr = w2 + (i4 * 4) * 32 + cg * 4;
#pragma unroll
            for (int j = 0; j < 4; ++j) {
                float4v wv = *(const float4v*)(wr + j * 32);
                acc[0] = fmaf(xv[j], wv[0], acc[0]);
                acc[1] = fmaf(xv[j], wv[1], acc[1]);
                acc[2] = fmaf(xv[j], wv[2], acc[2]);
                acc[3] = fmaf(xv[j], wv[3], acc[3]);
            }
        }
        half4v h;
        h[0] = (_Float16)fmaxf(acc[0], 0.f);
        h[1] = (_Float16)fmaxf(acc[1], 0.f);
        h[2] = (_Float16)fmaxf(acc[2], 0.f);
        h[3] = (_Float16)fmaxf(acc[3], 0.f);
        *(half4v*)(xcatH + (size_t)p * 96 + cg * 4) = h;
        return;
    }

    const float* src = (z == 1) ? a4s : a32s;
    const int   S    = (z == 1) ? 96 : 24;
    const float inv  = (z == 1) ? 0.5f : 0.125f;
    const int   coff = (z == 1) ? 32 : 64;

    int x = p % HA;
    int r = p / HA;
    int y = r % HA;
    int b = r / HA;

    float u = ((float)y + 0.5f) * inv - 0.5f;
    float v = ((float)x + 0.5f) * inv - 0.5f;
    float fu = floorf(u), fv = floorf(v);
    float wu = u - fu, wv = v - fv;
    int y0 = (int)fu, x0 = (int)fv;
    int y1 = min(y0 + 1, S - 1);
    int x1 = min(x0 + 1, S - 1);
    y0 = max(y0, 0);
    x0 = max(x0, 0);

    const float* sb = src + (size_t)b * S * S * 32 + cg * 4;
    float4v v00 = *(const float4v*)(sb + (y0 * S + x0) * 32);
    float4v v01 = *(const float4v*)(sb + (y0 * S + x1) * 32);
    float4v v10 = *(const float4v*)(sb + (y1 * S + x0) * 32);
    float4v v11 = *(const float4v*)(sb + (y1 * S + x1) * 32);
    half4v h;
#pragma unroll
    for (int j = 0; j < 4; ++j) {
        float t0 = v00[j] * (1.f - wu) + v10[j] * wu;
        float t1 = v01[j] * (1.f - wu) + v11[j] * wu;
        h[j] = (_Float16)(t0 * (1.f - wv) + t1 * wv);
    }
    *(half4v*)(xcatH + (size_t)p * 96 + coff + cg * 4) = h;
}

// ---- K3: 3x3 conv 96->96 + bias + ReLU via fp16 MFMA, fp16 in/out ---------
__launch_bounds__(256, 4)
__global__ void conv3x3_mfma(const _Float16* __restrict__ xH,
                             const _Float16* __restrict__ fragTabW,
                             const float* __restrict__ bias,
                             _Float16* __restrict__ yH) {
    __shared__ _Float16 lds[10 * 18 * 104];
    const int tid = threadIdx.x;
    const int lane = tid & 63;
    const int wv   = tid >> 6;
    const int n_   = lane & 15;
    const int qd   = lane >> 4;
    const int nh   = wv & 1;
    const int yg   = wv >> 1;
    const int bx0  = blockIdx.x * 16;
    const int by0  = blockIdx.y * 8;
    const int b    = blockIdx.z;

    for (int idx = tid; idx < 2160; idx += 256) {
        int hy  = idx / 216;
        int rem = idx - hy * 216;
        int hx  = rem / 12;
        int cc  = rem - hx * 12;
        int gy = by0 + hy - 1, gx = bx0 + hx - 1;
        half8 v = {(_Float16)0.f, (_Float16)0.f, (_Float16)0.f, (_Float16)0.f,
                   (_Float16)0.f, (_Float16)0.f, (_Float16)0.f, (_Float16)0.f};
        if (gy >= 0 && gy < HA && gx >= 0 && gx < HA)
            v = *(const half8*)(xH + (((size_t)b * HA + gy) * HA + gx) * 96 + cc * 8);
        *(half8*)&lds[(hy * 18 + hx) * 104 + cc * 8] = v;
    }

    float bv[3];
#pragma unroll
    for (int j = 0; j < 3; ++j) bv[j] = bias[(nh * 3 + j) * 16 + n_];

    __syncthreads();

    float4v acc[4][3];
#pragma unroll
    for (int r = 0; r < 4; ++r)
#pragma unroll
        for (int j = 0; j < 3; ++j) {
            float4v z = {0.f, 0.f, 0.f, 0.f};
            acc[r][j] = z;
        }

#pragma unroll 1
    for (int ky = 0; ky < 3; ++ky)
#pragma unroll 1
        for (int kx = 0; kx < 3; ++kx) {
            const int tap = ky * 3 + kx;
#pragma unroll
            for (int kc = 0; kc < 3; ++kc) {
                const int s = tap * 3 + kc;
                half8 bf[3];
#pragma unroll
                for (int j = 0; j < 3; ++j)
                    bf[j] = *(const half8*)(fragTabW +
                            ((size_t)(s * 6 + nh * 3 + j) * 64 + lane) * 8);
#pragma unroll
                for (int r = 0; r < 4; ++r) {
                    const int yr = yg * 4 + r;
                    half8 a = *(const half8*)&lds[((yr + ky) * 18 + (n_ + kx)) * 104
                                                  + kc * 32 + qd * 8];
#pragma unroll
                    for (int j = 0; j < 3; ++j)
                        acc[r][j] = __builtin_amdgcn_mfma_f32_16x16x32_f16(
                            a, bf[j], acc[r][j], 0, 0, 0);
                }
            }
        }

#pragma unroll
    for (int r = 0; r < 4; ++r) {
        const int gy = by0 + yg * 4 + r;
#pragma unroll
        for (int j = 0; j < 3; ++j) {
            const int ch = (nh * 3 + j) * 16 + n_;
#pragma unroll
            for (int reg = 0; reg < 4; ++reg) {
                const int gx = bx0 + qd * 4 + reg;
                yH[(((size_t)b * HA + gy) * HA + gx) * 96 + ch] =
                    (_Float16)fmaxf(acc[r][j][reg] + bv[j], 0.f);
            }
        }
    }
}

// ---- K4: sorted gather + MLP, barrier-free, 8 blocks/CU -------------------
__launch_bounds__(256, 8)
__global__ void decoder_mlp_mfma(const _Float16* __restrict__ asppH,
                                 const int* __restrict__ qidx,
                                 const float4v* __restrict__ qdata,
                                 const _Float16* __restrict__ fragTab,
                                 const float* __restrict__ mb0,
                                 const float* __restrict__ mb1,
                                 const float* __restrict__ mw2,
                                 const float* __restrict__ mb2,
                                 float* __restrict__ out) {
    __shared__ _Float16 Hb[64 * 64];   // 8 KB, wave-local 16x64 slices

    const int tid  = threadIdx.x;
    const int lane = tid & 63;
    const int wv   = tid >> 6;
    const int n_   = lane & 15;
    const int qd   = lane >> 4;
    const int r    = (blockIdx.x & 7) * 2304 + (blockIdx.x >> 3);
    const int m0   = wv * 16;

    // ---- per-lane corner data for row m0+n_ (query m0/4 + n_/4, corner n_&3)
    const int sp = r * 16 + (m0 >> 2) + (n_ >> 2);
    const float4v d = qdata[sp];
    const int   qq = qidx[sp];
    const int   b  = qq / (HQ * HQ);
    const float cy = d[0], cx = d[1], rcy = d[2], rcx = d[3];
    const int   k  = n_ & 3;

    const float LO = -1.0f + 1e-7f, HI = 1.0f - 1e-7f;
    const float RXY = 1.0f / (float)HA;
    const float vy = (k < 2) ? -1.f : 1.f;
    const float vx = (k & 1) ? 1.f : -1.f;

    float c0 = fminf(fmaxf((cy + vy * RXY) + 1e-7f, LO), HI);
    float c1 = fminf(fmaxf((cx + vx * RXY) + 1e-7f, LO), HI);
    int iy = (int)rintf(((c0 + 1.f) * (float)HA) * 0.5f - 0.5f);
    int ix = (int)rintf(((c1 + 1.f) * (float)HA) * 0.5f - 0.5f);
    iy = min(max(iy, 0), HA - 1);
    ix = min(max(ix, 0), HA - 1);

    const float cs0 = (((float)iy + 0.5f) / (float)HA) * 2.f - 1.f;
    const float cs1 = (((float)ix + 0.5f) / (float)HA) * 2.f - 1.f;
    const float r0 = (cy - cs0) * (float)HA;
    const float r1 = (cx - cs1) * (float)HA;
    const float area = fabsf(r0 * r1) + 1e-7f;
    const int   pix = ((b * HA + iy) * HA + ix) * 96;

    // ---- A fragments: kc=0..2 direct gather; kc=3 = extras in-register ----
    half8 A_[4];
    A_[0] = *(const half8*)(asppH + pix + 0 * 32 + qd * 8);
    A_[1] = *(const half8*)(asppH + pix + 1 * 32 + qd * 8);
    A_[2] = *(const half8*)(asppH + pix + 2 * 32 + qd * 8);
    {
        half8 e = {(_Float16)0.f, (_Float16)0.f, (_Float16)0.f, (_Float16)0.f,
                   (_Float16)0.f, (_Float16)0.f, (_Float16)0.f, (_Float16)0.f};
        if (qd == 0) {
            e[0] = (_Float16)r0;  e[1] = (_Float16)r1;
            e[2] = (_Float16)cy;  e[3] = (_Float16)cx;
            e[4] = (_Float16)rcy; e[5] = (_Float16)rcx;
        }
        A_[3] = e;
    }

    // ---- biases / layer2 weights (col = n_ per C layout) ----
    float mb0v[4], mb1v[4], w2v[4];
#pragma unroll
    for (int nt = 0; nt < 4; ++nt) {
        mb0v[nt] = mb0[nt * 16 + n_];
        mb1v[nt] = mb1[nt * 16 + n_];
        w2v[nt]  = mw2[nt * 16 + n_];
    }
    const float mb2s = mb2[0];

    // ---- layer0: 16 MFMAs ----
    float4v acc[4];
#pragma unroll
    for (int nt = 0; nt < 4; ++nt) {
        float4v t = {mb0v[nt], mb0v[nt], mb0v[nt], mb0v[nt]};
        acc[nt] = t;
    }
#pragma unroll
    for (int kc = 0; kc < 4; ++kc)
#pragma unroll
        for (int nt = 0; nt < 4; ++nt) {
            half8 b0 = *(const half8*)(fragTab +
                        ((size_t)(kc * 4 + nt) * 64 + lane) * 8);
            acc[nt] = __builtin_amdgcn_mfma_f32_16x16x32_f16(A_[kc], b0,
                                                             acc[nt], 0, 0, 0);
        }

    // ---- relu -> Hb (wave-local swizzled slice) ----
#pragma unroll
    for (int nt = 0; nt < 4; ++nt)
#pragma unroll
        for (int reg = 0; reg < 4; ++reg) {
            const int hr = m0 + qd * 4 + reg;
            const int nn = nt * 16 + n_;
            Hb[hr * 64 + (((nn >> 3) ^ (hr & 7)) * 8) + (nn & 7)] =
                (_Float16)fmaxf(acc[nt][reg], 0.f);
        }
    __builtin_amdgcn_s_waitcnt(0);   // drain LDS writes (wave-local dep)

    // ---- layer1: 8 MFMAs ----
    const int row = m0 + n_;
    float4v acc1[4];
#pragma unroll
    for (int nt = 0; nt < 4; ++nt) {
        float4v t = {mb1v[nt], mb1v[nt], mb1v[nt], mb1v[nt]};
        acc1[nt] = t;
    }
#pragma unroll
    for (int kc = 0; kc < 2; ++kc) {
        half8 a1 = *(const half8*)&Hb[row * 64 + (((kc * 4 + qd) ^ (row & 7)) * 8)];
#pragma unroll
        for (int nt = 0; nt < 4; ++nt) {
            half8 b1 = *(const half8*)(fragTab +
                        ((size_t)(16 + kc * 4 + nt) * 64 + lane) * 8);
            acc1[nt] = __builtin_amdgcn_mfma_f32_16x16x32_f16(a1, b1,
                                                              acc1[nt], 0, 0, 0);
        }
    }

    // ---- layer2 + in-wave combine ----
    float p[4];
#pragma unroll
    for (int reg = 0; reg < 4; ++reg) {
        float s = 0.f;
#pragma unroll
        for (int nt = 0; nt < 4; ++nt)
            s = fmaf(fmaxf(acc1[nt][reg], 0.f), w2v[nt], s);
        s += __shfl_xor(s, 1, 64);
        s += __shfl_xor(s, 2, 64);
        s += __shfl_xor(s, 4, 64);
        s += __shfl_xor(s, 8, 64);
        p[reg] = s + mb2s;      // pred of row m0 + qd*4 + reg
    }

    // areas of rows qd*4+k live in lanes (qd'=0, n_=qd*4+k)
    float a0s = __shfl(area, qd * 4 + 0, 64);
    float a1s = __shfl(area, qd * 4 + 1, 64);
    float a2s = __shfl(area, qd * 4 + 2, 64);
    float a3s = __shfl(area, qd * 4 + 3, 64);
    int   oq  = __shfl(qq,   qd * 4, 64);   // qidx of query m0/4 + qd

    if (n_ == 0) {
        float num = p[0] * a3s + p[1] * a2s + p[2] * a1s + p[3] * a0s;
        float den = a0s + a1s + a2s + a3s;
        out[oq] = num / den;
    }
}

// ---------------------------------------------------------------------------
extern "C" void kernel_launch(void* const* d_in, const int* in_sizes, int n_in,
                              void* d_out, int out_size, void* d_ws, size_t ws_size,
                              hipStream_t stream) {
    (void)in_sizes; (void)n_in; (void)out_size; (void)ws_size;
    const float* feats2  = (const float*)d_in[0];
    const float* feats4  = (const float*)d_in[1];
    const float* feats32 = (const float*)d_in[2];
    const float* coords  = (const float*)d_in[3];
    const float* cells   = (const float*)d_in[4];
    const float* w2  = (const float*)d_in[5];
    const float* b2  = (const float*)d_in[6];
    const float* w4  = (const float*)d_in[7];
    const float* b4  = (const float*)d_in[8];
    const float* w32 = (const float*)d_in[9];
    const float* b32 = (const float*)d_in[10];
    const float* wf  = (const float*)d_in[11];
    const float* bf  = (const float*)d_in[12];
    const float* mw0 = (const float*)d_in[13];
    const float* mb0 = (const float*)d_in[14];
    const float* mw1 = (const float*)d_in[15];
    const float* mb1 = (const float*)d_in[16];
    const float* mw2 = (const float*)d_in[17];
    const float* mb2 = (const float*)d_in[18];

    float* ws = (float*)d_ws;
    float*    a4s   = ws;                          // 589824 f
    float*    a32s  = a4s + 589824;                // 36864 f
    _Float16* xcatH = (_Float16*)(a32s + 36864);   // 7,077,888 h
    _Float16* asppH = xcatH + 7077888;             // 7,077,888 h
    _Float16* fragTab  = asppH + 7077888;          // 12,288 h
    _Float16* fragTabW = fragTab + 12288;          // 82,944 h
    float4v*  qdata = (float4v*)(fragTabW + 82944);   // NQ * 16 B
    int*      qidx  = (int*)(qdata + NQ);             // NQ ints
    int*      cntT  = qidx + NQ;                      // NFLAT ints
    int*      scanEx = cntT + NFLAT;                  // NFLAT ints
    int*      partials = scanEx + NFLAT;              // 81 ints (pad 128)
    unsigned short* lrank = (unsigned short*)(partials + 128);  // NQ u16
    float* out = (float*)d_out;

    prep_all<<<47, 256, 0, stream>>>(mw0, mw1, wf, fragTab, fragTabW);
    sort_count<<<NBS, 1024, 0, stream>>>(coords, cntT, lrank);
    scan_chunks<<<NFLAT / 1024, 1024, 0, stream>>>(cntT, scanEx, partials);
    scan_partials<<<1, 128, 0, stream>>>(partials);
    sort_scatter<<<NBS, 1024, 0, stream>>>(coords, cells, scanEx, partials,
                                           lrank, qidx, qdata);
    conv1x1_ab<<<612, 256, 0, stream>>>(feats4, w4, b4, feats32, w32, b32,
                                        a4s, a32s);
    build_xcat<<<dim3(2304, 3), 256, 0, stream>>>(feats2, w2, b2, a4s, a32s,
                                                  xcatH);
    conv3x3_mfma<<<dim3(12, 24, 2), 256, 0, stream>>>(xcatH, fragTabW, bf, asppH);
    decoder_mlp_mfma<<<18432, 256, 0, stream>>>(asppH, qidx, qdata, fragTab,
                                                mb0, mb1, mw2, mb2, out);
}

// Round 14
// 233.984 us; speedup vs baseline: 2.9782x; 1.0890x over previous
//
#include <hip/hip_runtime.h>
#include <math.h>

// ---------------------------------------------------------------------------
// Decoder_82764019794508: LIIF-style decoder.
// R14: launch-chain collapse 9 -> 4. Non-decoder wall time (~170us) exceeds
// the sum of per-kernel roofline estimates (~55us) -> serialized launch gaps.
// Fuse independent stages as grid sections:
//   K1 fused_front (1024t): sort_count + prep + conv1x1(a4s,a32s) + xcat z0
//   K2 fused_mid   (1024t): scan_chunks + upsample z1 + upsample z2
//   K3 fused_back  (256t):  conv3x3_mfma + sort_scatter (inline 81-prefix)
//   K4 decoder (R13, unchanged)
// All arithmetic and sort order unchanged -> bit-identical output.
// ---------------------------------------------------------------------------

#define HQ 384
#define HA 192
#define NQ (2 * HQ * HQ)   // 294912 queries
#define NBS (NQ / 1024)    // 288 sort blocks (1024 threads each)
#define NBKT 288           // 2 batches x 12x12 tiles of 16x16 px
#define NFLAT (NBKT * NBS) // 82944 = 81 * 1024

typedef _Float16 half8  __attribute__((ext_vector_type(8)));
typedef _Float16 half4v __attribute__((ext_vector_type(4)));
typedef float    float4v __attribute__((ext_vector_type(4)));

// bucket id from query coords: corner k=0 (vy=vx=-1) pixel, 16x16 tiles
__device__ __forceinline__ int bucket_id(int q, float cy, float cx) {
    const float LO = -1.0f + 1e-7f, HI = 1.0f - 1e-7f;
    const float RXY = 1.0f / (float)HA;
    float c0 = fminf(fmaxf((cy - RXY) + 1e-7f, LO), HI);
    float c1 = fminf(fmaxf((cx - RXY) + 1e-7f, LO), HI);
    int iy = (int)rintf(((c0 + 1.f) * (float)HA) * 0.5f - 0.5f);
    int ix = (int)rintf(((c1 + 1.f) * (float)HA) * 0.5f - 0.5f);
    iy = min(max(iy, 0), HA - 1);
    ix = min(max(ix, 0), HA - 1);
    int b = q / (HQ * HQ);
    return b * 144 + (iy >> 4) * 12 + (ix >> 4);
}

// ===========================================================================
// K1: fused_front — sort_count | prep frags | conv1x1 a4s/a32s | xcat z0
// blocks: [0,288) count | [288,300) prep | [300,444) f4 | [444,453) f32 |
//         [453,1029) xcat z0.   1024 threads.
// ===========================================================================
__launch_bounds__(1024)
__global__ void fused_front(const float* __restrict__ coords,
                            int* __restrict__ cntT,
                            unsigned short* __restrict__ lrank,
                            const float* __restrict__ mw0,
                            const float* __restrict__ mw1,
                            const float* __restrict__ wf,
                            _Float16* __restrict__ fragTab,
                            _Float16* __restrict__ fragTabW,
                            const float* __restrict__ feats4,
                            const float* __restrict__ w4,
                            const float* __restrict__ b4,
                            const float* __restrict__ feats32,
                            const float* __restrict__ w32,
                            const float* __restrict__ b32,
                            float* __restrict__ a4s,
                            float* __restrict__ a32s,
                            const float* __restrict__ feats2,
                            const float* __restrict__ w2,
                            const float* __restrict__ b2,
                            _Float16* __restrict__ xcatH) {
    const int blk = blockIdx.x;
    const int tid = threadIdx.x;

    if (blk < 288) {
        // ---- sort_count ----
        __shared__ int lh[NBKT];
        if (tid < NBKT) lh[tid] = 0;
        __syncthreads();
        const int q = blk * 1024 + tid;
        float cy = coords[(size_t)q * 2 + 0];
        float cx = coords[(size_t)q * 2 + 1];
        int r = atomicAdd(&lh[bucket_id(q, cy, cx)], 1);
        lrank[q] = (unsigned short)r;
        __syncthreads();
        if (tid < NBKT) cntT[tid * NBS + blk] = lh[tid];
    } else if (blk < 300) {
        // ---- prep frags ----
        int t = (blk - 288) * 1024 + tid;
        if (t < 1536) {
            int f = t >> 6, L = t & 63;
            int n_ = L & 15, qd = L >> 4;
            _Float16 vals[8];
            if (f < 16) {
                int kc = f >> 2, nt = f & 3;
#pragma unroll
                for (int j = 0; j < 8; ++j) {
                    int kk = kc * 32 + qd * 8 + j;
                    vals[j] = (_Float16)((kk < 102) ? mw0[kk * 64 + nt * 16 + n_] : 0.f);
                }
            } else {
                int g = f - 16;
                int kc = g >> 2, nt = g & 3;
#pragma unroll
                for (int j = 0; j < 8; ++j) {
                    int kk = kc * 32 + qd * 8 + j;
                    vals[j] = (_Float16)mw1[kk * 64 + nt * 16 + n_];
                }
            }
#pragma unroll
            for (int j = 0; j < 8; ++j) fragTab[t * 8 + j] = vals[j];
        } else {
            int tw = t - 1536;
            if (tw < 27 * 6 * 64) {
                int s   = tw / 384;
                int rem = tw - s * 384;
                int nt  = rem >> 6;
                int L   = rem & 63;
                int n_  = L & 15, qd = L >> 4;
                int tap = s / 3, kc = s - tap * 3;
#pragma unroll
                for (int j = 0; j < 8; ++j) {
                    int kch = kc * 32 + qd * 8 + j;
                    fragTabW[tw * 8 + j] =
                        (_Float16)wf[(tap * 96 + kch) * 96 + nt * 16 + n_];
                }
            }
        }
    } else if (blk < 444) {
        // ---- conv1x1 feats4 (96->32), 4 ch/thread ----
        int t = (blk - 300) * 1024 + tid;
        int p = t >> 3, cg = t & 7;
        const float4v* xr = (const float4v*)(feats4 + (size_t)p * 96);
        float4v acc = *(const float4v*)(b4 + cg * 4);
#pragma unroll
        for (int i4 = 0; i4 < 24; ++i4) {
            float4v xv = xr[i4];
            const float* wr = w4 + (i4 * 4) * 32 + cg * 4;
#pragma unroll
            for (int j = 0; j < 4; ++j) {
                float4v wv = *(const float4v*)(wr + j * 32);
                acc[0] = fmaf(xv[j], wv[0], acc[0]);
                acc[1] = fmaf(xv[j], wv[1], acc[1]);
                acc[2] = fmaf(xv[j], wv[2], acc[2]);
                acc[3] = fmaf(xv[j], wv[3], acc[3]);
            }
        }
        float4v o = {fmaxf(acc[0], 0.f), fmaxf(acc[1], 0.f),
                     fmaxf(acc[2], 0.f), fmaxf(acc[3], 0.f)};
        *(float4v*)(a4s + (size_t)p * 32 + cg * 4) = o;
    } else if (blk < 453) {
        // ---- conv1x1 feats32 (160->32), 4 ch/thread ----
        int t = (blk - 444) * 1024 + tid;
        if (t >= 1152 * 8) return;
        int p = t >> 3, cg = t & 7;
        const float4v* xr = (const float4v*)(feats32 + (size_t)p * 160);
        float4v acc = *(const float4v*)(b32 + cg * 4);
#pragma unroll
        for (int i4 = 0; i4 < 40; ++i4) {
            float4v xv = xr[i4];
            const float* wr = w32 + (i4 * 4) * 32 + cg * 4;
#pragma unroll
            for (int j = 0; j < 4; ++j) {
                float4v wv = *(const float4v*)(wr + j * 32);
                acc[0] = fmaf(xv[j], wv[0], acc[0]);
                acc[1] = fmaf(xv[j], wv[1], acc[1]);
                acc[2] = fmaf(xv[j], wv[2], acc[2]);
                acc[3] = fmaf(xv[j], wv[3], acc[3]);
            }
        }
        float4v o = {fmaxf(acc[0], 0.f), fmaxf(acc[1], 0.f),
                     fmaxf(acc[2], 0.f), fmaxf(acc[3], 0.f)};
        *(float4v*)(a32s + (size_t)p * 32 + cg * 4) = o;
    } else {
        // ---- xcat slice 0: conv1x1 feats2 (64->32) + ReLU, fp16 out ----
        int t = (blk - 453) * 1024 + tid;
        int p = t >> 3, cg = t & 7;
        const float4v* xr = (const float4v*)(feats2 + (size_t)p * 64);
        float4v acc = *(const float4v*)(b2 + cg * 4);
#pragma unroll
        for (int i4 = 0; i4 < 16; ++i4) {
            float4v xv = xr[i4];
            const float* wr = w2 + (i4 * 4) * 32 + cg * 4;
#pragma unroll
            for (int j = 0; j < 4; ++j) {
                float4v wv = *(const float4v*)(wr + j * 32);
                acc[0] = fmaf(xv[j], wv[0], acc[0]);
                acc[1] = fmaf(xv[j], wv[1], acc[1]);
                acc[2] = fmaf(xv[j], wv[2], acc[2]);
                acc[3] = fmaf(xv[j], wv[3], acc[3]);
            }
        }
        half4v h;
        h[0] = (_Float16)fmaxf(acc[0], 0.f);
        h[1] = (_Float16)fmaxf(acc[1], 0.f);
        h[2] = (_Float16)fmaxf(acc[2], 0.f);
        h[3] = (_Float16)fmaxf(acc[3], 0.f);
        *(half4v*)(xcatH + (size_t)p * 96 + cg * 4) = h;
    }
}

// ===========================================================================
// K2: fused_mid — scan_chunks | upsample z1 | upsample z2
// blocks: [0,81) scan | [81,657) z1 | [657,1233) z2.   1024 threads.
// ===========================================================================
__launch_bounds__(1024)
__global__ void fused_mid(const int* __restrict__ cntT,
                          int* __restrict__ scanEx,
                          int* __restrict__ chunkTot,
                          const float* __restrict__ a4s,
                          const float* __restrict__ a32s,
                          _Float16* __restrict__ xcatH) {
    const int blk = blockIdx.x;
    const int t = threadIdx.x;

    if (blk < 81) {
        __shared__ int s[1024];
        const int gi = blk * 1024 + t;
        int v = cntT[gi];
        s[t] = v;
        __syncthreads();
        for (int off = 1; off < 1024; off <<= 1) {
            int x = (t >= off) ? s[t - off] : 0;
            __syncthreads();
            s[t] += x;
            __syncthreads();
        }
        scanEx[gi] = s[t] - v;
        if (t == 1023) chunkTot[blk] = s[t];
        return;
    }

    const int z = (blk < 81 + 576) ? 1 : 2;
    int tt = ((z == 1) ? (blk - 81) : (blk - 657)) * 1024 + t;
    int p = tt >> 3, cg = tt & 7;

    const float* src = (z == 1) ? a4s : a32s;
    const int   S    = (z == 1) ? 96 : 24;
    const float inv  = (z == 1) ? 0.5f : 0.125f;
    const int   coff = (z == 1) ? 32 : 64;

    int x = p % HA;
    int r = p / HA;
    int y = r % HA;
    int b = r / HA;

    float u = ((float)y + 0.5f) * inv - 0.5f;
    float v = ((float)x + 0.5f) * inv - 0.5f;
    float fu = floorf(u), fv = floorf(v);
    float wu = u - fu, wv = v - fv;
    int y0 = (int)fu, x0 = (int)fv;
    int y1 = min(y0 + 1, S - 1);
    int x1 = min(x0 + 1, S - 1);
    y0 = max(y0, 0);
    x0 = max(x0, 0);

    const float* sb = src + (size_t)b * S * S * 32 + cg * 4;
    float4v v00 = *(const float4v*)(sb + (y0 * S + x0) * 32);
    float4v v01 = *(const float4v*)(sb + (y0 * S + x1) * 32);
    float4v v10 = *(const float4v*)(sb + (y1 * S + x0) * 32);
    float4v v11 = *(const float4v*)(sb + (y1 * S + x1) * 32);
    half4v h;
#pragma unroll
    for (int j = 0; j < 4; ++j) {
        float t0 = v00[j] * (1.f - wu) + v10[j] * wu;
        float t1 = v01[j] * (1.f - wu) + v11[j] * wu;
        h[j] = (_Float16)(t0 * (1.f - wv) + t1 * wv);
    }
    *(half4v*)(xcatH + (size_t)p * 96 + coff + cg * 4) = h;
}

// ===========================================================================
// K3: fused_back — conv3x3_mfma | sort_scatter (inline 81-chunk prefix)
// blocks: [0,576) conv3x3 | [576,1728) scatter.   256 threads.
// ===========================================================================
__launch_bounds__(256, 4)
__global__ void fused_back(const _Float16* __restrict__ xH,
                           const _Float16* __restrict__ fragTabW,
                           const float* __restrict__ bias,
                           _Float16* __restrict__ yH,
                           const float* __restrict__ coords,
                           const float* __restrict__ cells,
                           const int* __restrict__ scanEx,
                           const int* __restrict__ chunkTot,
                           const unsigned short* __restrict__ lrank,
                           int* __restrict__ qidx,
                           float4v* __restrict__ qdata) {
    __shared__ __align__(16) unsigned char smemU[37440];
    const int blk = blockIdx.x;
    const int tid = threadIdx.x;

    if (blk < 576) {
        // ---- conv3x3 (flattened grid: bx 12, by 24, b 2) ----
        _Float16* lds = (_Float16*)smemU;
        const int lane = tid & 63;
        const int wv   = tid >> 6;
        const int n_   = lane & 15;
        const int qd   = lane >> 4;
        const int nh   = wv & 1;
        const int yg   = wv >> 1;
        const int bx0  = (blk % 12) * 16;
        const int by0  = ((blk / 12) % 24) * 8;
        const int b    = blk / 288;

        for (int idx = tid; idx < 2160; idx += 256) {
            int hy  = idx / 216;
            int rem = idx - hy * 216;
            int hx  = rem / 12;
            int cc  = rem - hx * 12;
            int gy = by0 + hy - 1, gx = bx0 + hx - 1;
            half8 v = {(_Float16)0.f, (_Float16)0.f, (_Float16)0.f, (_Float16)0.f,
                       (_Float16)0.f, (_Float16)0.f, (_Float16)0.f, (_Float16)0.f};
            if (gy >= 0 && gy < HA && gx >= 0 && gx < HA)
                v = *(const half8*)(xH + (((size_t)b * HA + gy) * HA + gx) * 96 + cc * 8);
            *(half8*)&lds[(hy * 18 + hx) * 104 + cc * 8] = v;
        }

        float bv[3];
#pragma unroll
        for (int j = 0; j < 3; ++j) bv[j] = bias[(nh * 3 + j) * 16 + n_];

        __syncthreads();

        float4v acc[4][3];
#pragma unroll
        for (int r = 0; r < 4; ++r)
#pragma unroll
            for (int j = 0; j < 3; ++j) {
                float4v z = {0.f, 0.f, 0.f, 0.f};
                acc[r][j] = z;
            }

#pragma unroll 1
        for (int ky = 0; ky < 3; ++ky)
#pragma unroll 1
            for (int kx = 0; kx < 3; ++kx) {
                const int tap = ky * 3 + kx;
#pragma unroll
                for (int kc = 0; kc < 3; ++kc) {
                    const int s = tap * 3 + kc;
                    half8 bf[3];
#pragma unroll
                    for (int j = 0; j < 3; ++j)
                        bf[j] = *(const half8*)(fragTabW +
                                ((size_t)(s * 6 + nh * 3 + j) * 64 + lane) * 8);
#pragma unroll
                    for (int r = 0; r < 4; ++r) {
                        const int yr = yg * 4 + r;
                        half8 a = *(const half8*)&lds[((yr + ky) * 18 + (n_ + kx)) * 104
                                                      + kc * 32 + qd * 8];
#pragma unroll
                        for (int j = 0; j < 3; ++j)
                            acc[r][j] = __builtin_amdgcn_mfma_f32_16x16x32_f16(
                                a, bf[j], acc[r][j], 0, 0, 0);
                    }
                }
            }

#pragma unroll
        for (int r = 0; r < 4; ++r) {
            const int gy = by0 + yg * 4 + r;
#pragma unroll
            for (int j = 0; j < 3; ++j) {
                const int ch = (nh * 3 + j) * 16 + n_;
#pragma unroll
                for (int reg = 0; reg < 4; ++reg) {
                    const int gx = bx0 + qd * 4 + reg;
                    yH[(((size_t)b * HA + gy) * HA + gx) * 96 + ch] =
                        (_Float16)fmaxf(acc[r][j][reg] + bv[j], 0.f);
                }
            }
        }
    } else {
        // ---- sort_scatter with in-block exclusive prefix of 81 totals ----
        int* pEx = (int*)smemU;   // 128 ints
        int v = 0;
        if (tid < 81) v = chunkTot[tid];
        if (tid < 128) pEx[tid] = v;
        __syncthreads();
        for (int off = 1; off < 128; off <<= 1) {
            int x = 0;
            if (tid < 128 && tid >= off) x = pEx[tid - off];
            __syncthreads();
            if (tid < 128) pEx[tid] += x;
            __syncthreads();
        }
        if (tid < 128) pEx[tid] -= v;   // inclusive -> exclusive
        __syncthreads();

        const int q = (blk - 576) * 256 + tid;
        float cy = coords[(size_t)q * 2 + 0];
        float cx = coords[(size_t)q * 2 + 1];
        int bkt = bucket_id(q, cy, cx);
        int sb  = q >> 10;               // originating 1024-thread sort block
        int li  = bkt * NBS + sb;
        int pos = pEx[li >> 10] + scanEx[li] + (int)lrank[q];
        qidx[pos] = q;
        float4v d = {cy, cx,
                     cells[(size_t)q * 2 + 0] * (float)HA,
                     cells[(size_t)q * 2 + 1] * (float)HA};
        qdata[pos] = d;
    }
}

// ===========================================================================
// K4: decoder — sorted gather + MLP, barrier-free (unchanged from R13)
// ===========================================================================
__launch_bounds__(256, 8)
__global__ void decoder_mlp_mfma(const _Float16* __restrict__ asppH,
                                 const int* __restrict__ qidx,
                                 const float4v* __restrict__ qdata,
                                 const _Float16* __restrict__ fragTab,
                                 const float* __restrict__ mb0,
                                 const float* __restrict__ mb1,
                                 const float* __restrict__ mw2,
                                 const float* __restrict__ mb2,
                                 float* __restrict__ out) {
    __shared__ _Float16 Hb[64 * 64];   // 8 KB, wave-local 16x64 slices

    const int tid  = threadIdx.x;
    const int lane = tid & 63;
    const int wv   = tid >> 6;
    const int n_   = lane & 15;
    const int qd   = lane >> 4;
    const int r    = (blockIdx.x & 7) * 2304 + (blockIdx.x >> 3);
    const int m0   = wv * 16;

    const int sp = r * 16 + (m0 >> 2) + (n_ >> 2);
    const float4v d = qdata[sp];
    const int   qq = qidx[sp];
    const int   b  = qq / (HQ * HQ);
    const float cy = d[0], cx = d[1], rcy = d[2], rcx = d[3];
    const int   k  = n_ & 3;

    const float LO = -1.0f + 1e-7f, HI = 1.0f - 1e-7f;
    const float RXY = 1.0f / (float)HA;
    const float vy = (k < 2) ? -1.f : 1.f;
    const float vx = (k & 1) ? 1.f : -1.f;

    float c0 = fminf(fmaxf((cy + vy * RXY) + 1e-7f, LO), HI);
    float c1 = fminf(fmaxf((cx + vx * RXY) + 1e-7f, LO), HI);
    int iy = (int)rintf(((c0 + 1.f) * (float)HA) * 0.5f - 0.5f);
    int ix = (int)rintf(((c1 + 1.f) * (float)HA) * 0.5f - 0.5f);
    iy = min(max(iy, 0), HA - 1);
    ix = min(max(ix, 0), HA - 1);

    const float cs0 = (((float)iy + 0.5f) / (float)HA) * 2.f - 1.f;
    const float cs1 = (((float)ix + 0.5f) / (float)HA) * 2.f - 1.f;
    const float r0 = (cy - cs0) * (float)HA;
    const float r1 = (cx - cs1) * (float)HA;
    const float area = fabsf(r0 * r1) + 1e-7f;
    const int   pix = ((b * HA + iy) * HA + ix) * 96;

    half8 A_[4];
    A_[0] = *(const half8*)(asppH + pix + 0 * 32 + qd * 8);
    A_[1] = *(const half8*)(asppH + pix + 1 * 32 + qd * 8);
    A_[2] = *(const half8*)(asppH + pix + 2 * 32 + qd * 8);
    {
        half8 e = {(_Float16)0.f, (_Float16)0.f, (_Float16)0.f, (_Float16)0.f,
                   (_Float16)0.f, (_Float16)0.f, (_Float16)0.f, (_Float16)0.f};
        if (qd == 0) {
            e[0] = (_Float16)r0;  e[1] = (_Float16)r1;
            e[2] = (_Float16)cy;  e[3] = (_Float16)cx;
            e[4] = (_Float16)rcy; e[5] = (_Float16)rcx;
        }
        A_[3] = e;
    }

    float mb0v[4], mb1v[4], w2v[4];
#pragma unroll
    for (int nt = 0; nt < 4; ++nt) {
        mb0v[nt] = mb0[nt * 16 + n_];
        mb1v[nt] = mb1[nt * 16 + n_];
        w2v[nt]  = mw2[nt * 16 + n_];
    }
    const float mb2s = mb2[0];

    float4v acc[4];
#pragma unroll
    for (int nt = 0; nt < 4; ++nt) {
        float4v t = {mb0v[nt], mb0v[nt], mb0v[nt], mb0v[nt]};
        acc[nt] = t;
    }
#pragma unroll
    for (int kc = 0; kc < 4; ++kc)
#pragma unroll
        for (int nt = 0; nt < 4; ++nt) {
            half8 b0 = *(const half8*)(fragTab +
                        ((size_t)(kc * 4 + nt) * 64 + lane) * 8);
            acc[nt] = __builtin_amdgcn_mfma_f32_16x16x32_f16(A_[kc], b0,
                                                             acc[nt], 0, 0, 0);
        }

#pragma unroll
    for (int nt = 0; nt < 4; ++nt)
#pragma unroll
        for (int reg = 0; reg < 4; ++reg) {
            const int hr = m0 + qd * 4 + reg;
            const int nn = nt * 16 + n_;
            Hb[hr * 64 + (((nn >> 3) ^ (hr & 7)) * 8) + (nn & 7)] =
                (_Float16)fmaxf(acc[nt][reg], 0.f);
        }
    __builtin_amdgcn_s_waitcnt(0);   // drain LDS writes (wave-local dep)

    const int row = m0 + n_;
    float4v acc1[4];
#pragma unroll
    for (int nt = 0; nt < 4; ++nt) {
        float4v t = {mb1v[nt], mb1v[nt], mb1v[nt], mb1v[nt]};
        acc1[nt] = t;
    }
#pragma unroll
    for (int kc = 0; kc < 2; ++kc) {
        half8 a1 = *(const half8*)&Hb[row * 64 + (((kc * 4 + qd) ^ (row & 7)) * 8)];
#pragma unroll
        for (int nt = 0; nt < 4; ++nt) {
            half8 b1 = *(const half8*)(fragTab +
                        ((size_t)(16 + kc * 4 + nt) * 64 + lane) * 8);
            acc1[nt] = __builtin_amdgcn_mfma_f32_16x16x32_f16(a1, b1,
                                                              acc1[nt], 0, 0, 0);
        }
    }

    float p[4];
#pragma unroll
    for (int reg = 0; reg < 4; ++reg) {
        float s = 0.f;
#pragma unroll
        for (int nt = 0; nt < 4; ++nt)
            s = fmaf(fmaxf(acc1[nt][reg], 0.f), w2v[nt], s);
        s += __shfl_xor(s, 1, 64);
        s += __shfl_xor(s, 2, 64);
        s += __shfl_xor(s, 4, 64);
        s += __shfl_xor(s, 8, 64);
        p[reg] = s + mb2s;
    }

    float a0s = __shfl(area, qd * 4 + 0, 64);
    float a1s = __shfl(area, qd * 4 + 1, 64);
    float a2s = __shfl(area, qd * 4 + 2, 64);
    float a3s = __shfl(area, qd * 4 + 3, 64);
    int   oq  = __shfl(qq,   qd * 4, 64);

    if (n_ == 0) {
        float num = p[0] * a3s + p[1] * a2s + p[2] * a1s + p[3] * a0s;
        float den = a0s + a1s + a2s + a3s;
        out[oq] = num / den;
    }
}

// ---------------------------------------------------------------------------
extern "C" void kernel_launch(void* const* d_in, const int* in_sizes, int n_in,
                              void* d_out, int out_size, void* d_ws, size_t ws_size,
                              hipStream_t stream) {
    (void)in_sizes; (void)n_in; (void)out_size; (void)ws_size;
    const float* feats2  = (const float*)d_in[0];
    const float* feats4  = (const float*)d_in[1];
    const float* feats32 = (const float*)d_in[2];
    const float* coords  = (const float*)d_in[3];
    const float* cells   = (const float*)d_in[4];
    const float* w2  = (const float*)d_in[5];
    const float* b2  = (const float*)d_in[6];
    const float* w4  = (const float*)d_in[7];
    const float* b4  = (const float*)d_in[8];
    const float* w32 = (const float*)d_in[9];
    const float* b32 = (const float*)d_in[10];
    const float* wf  = (const float*)d_in[11];
    const float* bf  = (const float*)d_in[12];
    const float* mw0 = (const float*)d_in[13];
    const float* mb0 = (const float*)d_in[14];
    const float* mw1 = (const float*)d_in[15];
    const float* mb1 = (const float*)d_in[16];
    const float* mw2 = (const float*)d_in[17];
    const float* mb2 = (const float*)d_in[18];

    float* ws = (float*)d_ws;
    float*    a4s   = ws;                          // 589824 f
    float*    a32s  = a4s + 589824;                // 36864 f
    _Float16* xcatH = (_Float16*)(a32s + 36864);   // 7,077,888 h
    _Float16* asppH = xcatH + 7077888;             // 7,077,888 h
    _Float16* fragTab  = asppH + 7077888;          // 12,288 h
    _Float16* fragTabW = fragTab + 12288;          // 82,944 h
    float4v*  qdata = (float4v*)(fragTabW + 82944);   // NQ * 16 B
    int*      qidx  = (int*)(qdata + NQ);             // NQ ints
    int*      cntT  = qidx + NQ;                      // NFLAT ints
    int*      scanEx = cntT + NFLAT;                  // NFLAT ints
    int*      chunkTot = scanEx + NFLAT;              // 81 ints (pad 128)
    unsigned short* lrank = (unsigned short*)(chunkTot + 128);  // NQ u16
    float* out = (float*)d_out;

    fused_front<<<1029, 1024, 0, stream>>>(coords, cntT, lrank,
                                           mw0, mw1, wf, fragTab, fragTabW,
                                           feats4, w4, b4, feats32, w32, b32,
                                           a4s, a32s, feats2, w2, b2, xcatH);
    fused_mid<<<1233, 1024, 0, stream>>>(cntT, scanEx, chunkTot,
                                         a4s, a32s, xcatH);
    fused_back<<<1728, 256, 0, stream>>>(xcatH, fragTabW, bf, asppH,
                                         coords, cells, scanEx, chunkTot,
                                         lrank, qidx, qdata);
    decoder_mlp_mfma<<<18432, 256, 0, stream>>>(asppH, qidx, qdata, fragTab,
                                                mb0, mb1, mw2, mb2, out);
}

// Round 15
// 224.683 us; speedup vs baseline: 3.1015x; 1.0414x over previous
//
#include <hip/hip_runtime.h>
#include <math.h>

// ---------------------------------------------------------------------------
// Decoder_82764019794508: LIIF-style decoder.
// R15: decoder weight fragments staged in LDS. Theory: per-wave 12.6 KB of
// fragTab/bias reads miss L1 (thrashed by the random gather) and stream
// ~11 TB/s from L2 — the hidden limiter that kept the decoder at 85us
// through 3 occupancy rounds. fragL (24.6 KB) + biases in LDS, read via
// ds_read_b128; LDS 33.5 KB -> 4 blocks/CU (occupancy provably not the
// limiter, per R13). Front/mid/back identical to R14. Numerics bit-identical.
// ---------------------------------------------------------------------------

#define HQ 384
#define HA 192
#define NQ (2 * HQ * HQ)   // 294912 queries
#define NBS (NQ / 1024)    // 288 sort blocks (1024 threads each)
#define NBKT 288           // 2 batches x 12x12 tiles of 16x16 px
#define NFLAT (NBKT * NBS) // 82944 = 81 * 1024

typedef _Float16 half8  __attribute__((ext_vector_type(8)));
typedef _Float16 half4v __attribute__((ext_vector_type(4)));
typedef float    float4v __attribute__((ext_vector_type(4)));

// bucket id from query coords: corner k=0 (vy=vx=-1) pixel, 16x16 tiles
__device__ __forceinline__ int bucket_id(int q, float cy, float cx) {
    const float LO = -1.0f + 1e-7f, HI = 1.0f - 1e-7f;
    const float RXY = 1.0f / (float)HA;
    float c0 = fminf(fmaxf((cy - RXY) + 1e-7f, LO), HI);
    float c1 = fminf(fmaxf((cx - RXY) + 1e-7f, LO), HI);
    int iy = (int)rintf(((c0 + 1.f) * (float)HA) * 0.5f - 0.5f);
    int ix = (int)rintf(((c1 + 1.f) * (float)HA) * 0.5f - 0.5f);
    iy = min(max(iy, 0), HA - 1);
    ix = min(max(ix, 0), HA - 1);
    int b = q / (HQ * HQ);
    return b * 144 + (iy >> 4) * 12 + (ix >> 4);
}

// ===========================================================================
// K1: fused_front — sort_count | prep frags | conv1x1 a4s/a32s | xcat z0
// ===========================================================================
__launch_bounds__(1024)
__global__ void fused_front(const float* __restrict__ coords,
                            int* __restrict__ cntT,
                            unsigned short* __restrict__ lrank,
                            const float* __restrict__ mw0,
                            const float* __restrict__ mw1,
                            const float* __restrict__ wf,
                            _Float16* __restrict__ fragTab,
                            _Float16* __restrict__ fragTabW,
                            const float* __restrict__ feats4,
                            const float* __restrict__ w4,
                            const float* __restrict__ b4,
                            const float* __restrict__ feats32,
                            const float* __restrict__ w32,
                            const float* __restrict__ b32,
                            float* __restrict__ a4s,
                            float* __restrict__ a32s,
                            const float* __restrict__ feats2,
                            const float* __restrict__ w2,
                            const float* __restrict__ b2,
                            _Float16* __restrict__ xcatH) {
    const int blk = blockIdx.x;
    const int tid = threadIdx.x;

    if (blk < 288) {
        __shared__ int lh[NBKT];
        if (tid < NBKT) lh[tid] = 0;
        __syncthreads();
        const int q = blk * 1024 + tid;
        float cy = coords[(size_t)q * 2 + 0];
        float cx = coords[(size_t)q * 2 + 1];
        int r = atomicAdd(&lh[bucket_id(q, cy, cx)], 1);
        lrank[q] = (unsigned short)r;
        __syncthreads();
        if (tid < NBKT) cntT[tid * NBS + blk] = lh[tid];
    } else if (blk < 300) {
        int t = (blk - 288) * 1024 + tid;
        if (t < 1536) {
            int f = t >> 6, L = t & 63;
            int n_ = L & 15, qd = L >> 4;
            _Float16 vals[8];
            if (f < 16) {
                int kc = f >> 2, nt = f & 3;
#pragma unroll
                for (int j = 0; j < 8; ++j) {
                    int kk = kc * 32 + qd * 8 + j;
                    vals[j] = (_Float16)((kk < 102) ? mw0[kk * 64 + nt * 16 + n_] : 0.f);
                }
            } else {
                int g = f - 16;
                int kc = g >> 2, nt = g & 3;
#pragma unroll
                for (int j = 0; j < 8; ++j) {
                    int kk = kc * 32 + qd * 8 + j;
                    vals[j] = (_Float16)mw1[kk * 64 + nt * 16 + n_];
                }
            }
#pragma unroll
            for (int j = 0; j < 8; ++j) fragTab[t * 8 + j] = vals[j];
        } else {
            int tw = t - 1536;
            if (tw < 27 * 6 * 64) {
                int s   = tw / 384;
                int rem = tw - s * 384;
                int nt  = rem >> 6;
                int L   = rem & 63;
                int n_  = L & 15, qd = L >> 4;
                int tap = s / 3, kc = s - tap * 3;
#pragma unroll
                for (int j = 0; j < 8; ++j) {
                    int kch = kc * 32 + qd * 8 + j;
                    fragTabW[tw * 8 + j] =
                        (_Float16)wf[(tap * 96 + kch) * 96 + nt * 16 + n_];
                }
            }
        }
    } else if (blk < 444) {
        int t = (blk - 300) * 1024 + tid;
        int p = t >> 3, cg = t & 7;
        const float4v* xr = (const float4v*)(feats4 + (size_t)p * 96);
        float4v acc = *(const float4v*)(b4 + cg * 4);
#pragma unroll
        for (int i4 = 0; i4 < 24; ++i4) {
            float4v xv = xr[i4];
            const float* wr = w4 + (i4 * 4) * 32 + cg * 4;
#pragma unroll
            for (int j = 0; j < 4; ++j) {
                float4v wv = *(const float4v*)(wr + j * 32);
                acc[0] = fmaf(xv[j], wv[0], acc[0]);
                acc[1] = fmaf(xv[j], wv[1], acc[1]);
                acc[2] = fmaf(xv[j], wv[2], acc[2]);
                acc[3] = fmaf(xv[j], wv[3], acc[3]);
            }
        }
        float4v o = {fmaxf(acc[0], 0.f), fmaxf(acc[1], 0.f),
                     fmaxf(acc[2], 0.f), fmaxf(acc[3], 0.f)};
        *(float4v*)(a4s + (size_t)p * 32 + cg * 4) = o;
    } else if (blk < 453) {
        int t = (blk - 444) * 1024 + tid;
        if (t >= 1152 * 8) return;
        int p = t >> 3, cg = t & 7;
        const float4v* xr = (const float4v*)(feats32 + (size_t)p * 160);
        float4v acc = *(const float4v*)(b32 + cg * 4);
#pragma unroll
        for (int i4 = 0; i4 < 40; ++i4) {
            float4v xv = xr[i4];
            const float* wr = w32 + (i4 * 4) * 32 + cg * 4;
#pragma unroll
            for (int j = 0; j < 4; ++j) {
                float4v wv = *(const float4v*)(wr + j * 32);
                acc[0] = fmaf(xv[j], wv[0], acc[0]);
                acc[1] = fmaf(xv[j], wv[1], acc[1]);
                acc[2] = fmaf(xv[j], wv[2], acc[2]);
                acc[3] = fmaf(xv[j], wv[3], acc[3]);
            }
        }
        float4v o = {fmaxf(acc[0], 0.f), fmaxf(acc[1], 0.f),
                     fmaxf(acc[2], 0.f), fmaxf(acc[3], 0.f)};
        *(float4v*)(a32s + (size_t)p * 32 + cg * 4) = o;
    } else {
        int t = (blk - 453) * 1024 + tid;
        int p = t >> 3, cg = t & 7;
        const float4v* xr = (const float4v*)(feats2 + (size_t)p * 64);
        float4v acc = *(const float4v*)(b2 + cg * 4);
#pragma unroll
        for (int i4 = 0; i4 < 16; ++i4) {
            float4v xv = xr[i4];
            const float* wr = w2 + (i4 * 4) * 32 + cg * 4;
#pragma unroll
            for (int j = 0; j < 4; ++j) {
                float4v wv = *(const float4v*)(wr + j * 32);
                acc[0] = fmaf(xv[j], wv[0], acc[0]);
                acc[1] = fmaf(xv[j], wv[1], acc[1]);
                acc[2] = fmaf(xv[j], wv[2], acc[2]);
                acc[3] = fmaf(xv[j], wv[3], acc[3]);
            }
        }
        half4v h;
        h[0] = (_Float16)fmaxf(acc[0], 0.f);
        h[1] = (_Float16)fmaxf(acc[1], 0.f);
        h[2] = (_Float16)fmaxf(acc[2], 0.f);
        h[3] = (_Float16)fmaxf(acc[3], 0.f);
        *(half4v*)(xcatH + (size_t)p * 96 + cg * 4) = h;
    }
}

// ===========================================================================
// K2: fused_mid — scan_chunks | upsample z1 | upsample z2
// ===========================================================================
__launch_bounds__(1024)
__global__ void fused_mid(const int* __restrict__ cntT,
                          int* __restrict__ scanEx,
                          int* __restrict__ chunkTot,
                          const float* __restrict__ a4s,
                          const float* __restrict__ a32s,
                          _Float16* __restrict__ xcatH) {
    const int blk = blockIdx.x;
    const int t = threadIdx.x;

    if (blk < 81) {
        __shared__ int s[1024];
        const int gi = blk * 1024 + t;
        int v = cntT[gi];
        s[t] = v;
        __syncthreads();
        for (int off = 1; off < 1024; off <<= 1) {
            int x = (t >= off) ? s[t - off] : 0;
            __syncthreads();
            s[t] += x;
            __syncthreads();
        }
        scanEx[gi] = s[t] - v;
        if (t == 1023) chunkTot[blk] = s[t];
        return;
    }

    const int z = (blk < 81 + 576) ? 1 : 2;
    int tt = ((z == 1) ? (blk - 81) : (blk - 657)) * 1024 + t;
    int p = tt >> 3, cg = tt & 7;

    const float* src = (z == 1) ? a4s : a32s;
    const int   S    = (z == 1) ? 96 : 24;
    const float inv  = (z == 1) ? 0.5f : 0.125f;
    const int   coff = (z == 1) ? 32 : 64;

    int x = p % HA;
    int r = p / HA;
    int y = r % HA;
    int b = r / HA;

    float u = ((float)y + 0.5f) * inv - 0.5f;
    float v = ((float)x + 0.5f) * inv - 0.5f;
    float fu = floorf(u), fv = floorf(v);
    float wu = u - fu, wv = v - fv;
    int y0 = (int)fu, x0 = (int)fv;
    int y1 = min(y0 + 1, S - 1);
    int x1 = min(x0 + 1, S - 1);
    y0 = max(y0, 0);
    x0 = max(x0, 0);

    const float* sb = src + (size_t)b * S * S * 32 + cg * 4;
    float4v v00 = *(const float4v*)(sb + (y0 * S + x0) * 32);
    float4v v01 = *(const float4v*)(sb + (y0 * S + x1) * 32);
    float4v v10 = *(const float4v*)(sb + (y1 * S + x0) * 32);
    float4v v11 = *(const float4v*)(sb + (y1 * S + x1) * 32);
    half4v h;
#pragma unroll
    for (int j = 0; j < 4; ++j) {
        float t0 = v00[j] * (1.f - wu) + v10[j] * wu;
        float t1 = v01[j] * (1.f - wu) + v11[j] * wu;
        h[j] = (_Float16)(t0 * (1.f - wv) + t1 * wv);
    }
    *(half4v*)(xcatH + (size_t)p * 96 + coff + cg * 4) = h;
}

// ===========================================================================
// K3: fused_back — conv3x3_mfma | sort_scatter (inline 81-chunk prefix)
// ===========================================================================
__launch_bounds__(256, 4)
__global__ void fused_back(const _Float16* __restrict__ xH,
                           const _Float16* __restrict__ fragTabW,
                           const float* __restrict__ bias,
                           _Float16* __restrict__ yH,
                           const float* __restrict__ coords,
                           const float* __restrict__ cells,
                           const int* __restrict__ scanEx,
                           const int* __restrict__ chunkTot,
                           const unsigned short* __restrict__ lrank,
                           int* __restrict__ qidx,
                           float4v* __restrict__ qdata) {
    __shared__ __align__(16) unsigned char smemU[37440];
    const int blk = blockIdx.x;
    const int tid = threadIdx.x;

    if (blk < 576) {
        _Float16* lds = (_Float16*)smemU;
        const int lane = tid & 63;
        const int wv   = tid >> 6;
        const int n_   = lane & 15;
        const int qd   = lane >> 4;
        const int nh   = wv & 1;
        const int yg   = wv >> 1;
        const int bx0  = (blk % 12) * 16;
        const int by0  = ((blk / 12) % 24) * 8;
        const int b    = blk / 288;

        for (int idx = tid; idx < 2160; idx += 256) {
            int hy  = idx / 216;
            int rem = idx - hy * 216;
            int hx  = rem / 12;
            int cc  = rem - hx * 12;
            int gy = by0 + hy - 1, gx = bx0 + hx - 1;
            half8 v = {(_Float16)0.f, (_Float16)0.f, (_Float16)0.f, (_Float16)0.f,
                       (_Float16)0.f, (_Float16)0.f, (_Float16)0.f, (_Float16)0.f};
            if (gy >= 0 && gy < HA && gx >= 0 && gx < HA)
                v = *(const half8*)(xH + (((size_t)b * HA + gy) * HA + gx) * 96 + cc * 8);
            *(half8*)&lds[(hy * 18 + hx) * 104 + cc * 8] = v;
        }

        float bv[3];
#pragma unroll
        for (int j = 0; j < 3; ++j) bv[j] = bias[(nh * 3 + j) * 16 + n_];

        __syncthreads();

        float4v acc[4][3];
#pragma unroll
        for (int r = 0; r < 4; ++r)
#pragma unroll
            for (int j = 0; j < 3; ++j) {
                float4v z = {0.f, 0.f, 0.f, 0.f};
                acc[r][j] = z;
            }

#pragma unroll 1
        for (int ky = 0; ky < 3; ++ky)
#pragma unroll 1
            for (int kx = 0; kx < 3; ++kx) {
                const int tap = ky * 3 + kx;
#pragma unroll
                for (int kc = 0; kc < 3; ++kc) {
                    const int s = tap * 3 + kc;
                    half8 bf[3];
#pragma unroll
                    for (int j = 0; j < 3; ++j)
                        bf[j] = *(const half8*)(fragTabW +
                                ((size_t)(s * 6 + nh * 3 + j) * 64 + lane) * 8);
#pragma unroll
                    for (int r = 0; r < 4; ++r) {
                        const int yr = yg * 4 + r;
                        half8 a = *(const half8*)&lds[((yr + ky) * 18 + (n_ + kx)) * 104
                                                      + kc * 32 + qd * 8];
#pragma unroll
                        for (int j = 0; j < 3; ++j)
                            acc[r][j] = __builtin_amdgcn_mfma_f32_16x16x32_f16(
                                a, bf[j], acc[r][j], 0, 0, 0);
                    }
                }
            }

#pragma unroll
        for (int r = 0; r < 4; ++r) {
            const int gy = by0 + yg * 4 + r;
#pragma unroll
            for (int j = 0; j < 3; ++j) {
                const int ch = (nh * 3 + j) * 16 + n_;
#pragma unroll
                for (int reg = 0; reg < 4; ++reg) {
                    const int gx = bx0 + qd * 4 + reg;
                    yH[(((size_t)b * HA + gy) * HA + gx) * 96 + ch] =
                        (_Float16)fmaxf(acc[r][j][reg] + bv[j], 0.f);
                }
            }
        }
    } else {
        int* pEx = (int*)smemU;   // 128 ints
        int v = 0;
        if (tid < 81) v = chunkTot[tid];
        if (tid < 128) pEx[tid] = v;
        __syncthreads();
        for (int off = 1; off < 128; off <<= 1) {
            int x = 0;
            if (tid < 128 && tid >= off) x = pEx[tid - off];
            __syncthreads();
            if (tid < 128) pEx[tid] += x;
            __syncthreads();
        }
        if (tid < 128) pEx[tid] -= v;   // inclusive -> exclusive
        __syncthreads();

        const int q = (blk - 576) * 256 + tid;
        float cy = coords[(size_t)q * 2 + 0];
        float cx = coords[(size_t)q * 2 + 1];
        int bkt = bucket_id(q, cy, cx);
        int sb  = q >> 10;
        int li  = bkt * NBS + sb;
        int pos = pEx[li >> 10] + scanEx[li] + (int)lrank[q];
        qidx[pos] = q;
        float4v d = {cy, cx,
                     cells[(size_t)q * 2 + 0] * (float)HA,
                     cells[(size_t)q * 2 + 1] * (float)HA};
        qdata[pos] = d;
    }
}

// ===========================================================================
// K4: decoder — sorted gather + MLP, weight frags staged in LDS
// LDS: fragL 24.6 KB + Hb 8 KB + biases 0.8 KB = 33.5 KB -> 4 blocks/CU.
// Gathers + corner math issued before the staging barrier (overlap).
// ===========================================================================
__launch_bounds__(256, 4)
__global__ void decoder_mlp_mfma(const _Float16* __restrict__ asppH,
                                 const int* __restrict__ qidx,
                                 const float4v* __restrict__ qdata,
                                 const _Float16* __restrict__ fragTab,
                                 const float* __restrict__ mb0,
                                 const float* __restrict__ mb1,
                                 const float* __restrict__ mw2,
                                 const float* __restrict__ mb2,
                                 float* __restrict__ out) {
    __shared__ __align__(16) _Float16 fragL[24 * 64 * 8];  // 24576 B
    __shared__ _Float16 Hb[64 * 64];                       // 8192 B
    __shared__ float biasL[196];                           // mb0|mb1|mw2|mb2

    const int tid  = threadIdx.x;
    const int lane = tid & 63;
    const int wv   = tid >> 6;
    const int n_   = lane & 15;
    const int qd   = lane >> 4;
    const int r    = (blockIdx.x & 7) * 2304 + (blockIdx.x >> 3);
    const int m0   = wv * 16;

    // ---- per-lane corner data (issued before staging barrier) ----
    const int sp = r * 16 + (m0 >> 2) + (n_ >> 2);
    const float4v d = qdata[sp];
    const int   qq = qidx[sp];
    const int   b  = qq / (HQ * HQ);
    const float cy = d[0], cx = d[1], rcy = d[2], rcx = d[3];
    const int   k  = n_ & 3;

    const float LO = -1.0f + 1e-7f, HI = 1.0f - 1e-7f;
    const float RXY = 1.0f / (float)HA;
    const float vy = (k < 2) ? -1.f : 1.f;
    const float vx = (k & 1) ? 1.f : -1.f;

    float c0 = fminf(fmaxf((cy + vy * RXY) + 1e-7f, LO), HI);
    float c1 = fminf(fmaxf((cx + vx * RXY) + 1e-7f, LO), HI);
    int iy = (int)rintf(((c0 + 1.f) * (float)HA) * 0.5f - 0.5f);
    int ix = (int)rintf(((c1 + 1.f) * (float)HA) * 0.5f - 0.5f);
    iy = min(max(iy, 0), HA - 1);
    ix = min(max(ix, 0), HA - 1);

    const float cs0 = (((float)iy + 0.5f) / (float)HA) * 2.f - 1.f;
    const float cs1 = (((float)ix + 0.5f) / (float)HA) * 2.f - 1.f;
    const float r0 = (cy - cs0) * (float)HA;
    const float r1 = (cx - cs1) * (float)HA;
    const float area = fabsf(r0 * r1) + 1e-7f;
    const int   pix = ((b * HA + iy) * HA + ix) * 96;

    // ---- A fragments: kc=0..2 direct gather; kc=3 = extras in-register ----
    half8 A_[4];
    A_[0] = *(const half8*)(asppH + pix + 0 * 32 + qd * 8);
    A_[1] = *(const half8*)(asppH + pix + 1 * 32 + qd * 8);
    A_[2] = *(const half8*)(asppH + pix + 2 * 32 + qd * 8);
    {
        half8 e = {(_Float16)0.f, (_Float16)0.f, (_Float16)0.f, (_Float16)0.f,
                   (_Float16)0.f, (_Float16)0.f, (_Float16)0.f, (_Float16)0.f};
        if (qd == 0) {
            e[0] = (_Float16)r0;  e[1] = (_Float16)r1;
            e[2] = (_Float16)cy;  e[3] = (_Float16)cx;
            e[4] = (_Float16)rcy; e[5] = (_Float16)rcx;
        }
        A_[3] = e;
    }

    // ---- cooperative staging: fragTab -> fragL (1536 half8), biases ----
#pragma unroll
    for (int it = 0; it < 6; ++it) {
        const int i = it * 256 + tid;
        *(half8*)&fragL[i * 8] = *(const half8*)(fragTab + (size_t)i * 8);
    }
    if (tid < 64) {
        biasL[tid]       = mb0[tid];
        biasL[64 + tid]  = mb1[tid];
        biasL[128 + tid] = mw2[tid];
    }
    if (tid == 0) biasL[192] = mb2[0];
    __syncthreads();

    float mb0v[4], mb1v[4], w2v[4];
#pragma unroll
    for (int nt = 0; nt < 4; ++nt) {
        mb0v[nt] = biasL[nt * 16 + n_];
        mb1v[nt] = biasL[64 + nt * 16 + n_];
        w2v[nt]  = biasL[128 + nt * 16 + n_];
    }
    const float mb2s = biasL[192];

    // ---- layer0: 16 MFMAs, B-frags from LDS ----
    float4v acc[4];
#pragma unroll
    for (int nt = 0; nt < 4; ++nt) {
        float4v t = {mb0v[nt], mb0v[nt], mb0v[nt], mb0v[nt]};
        acc[nt] = t;
    }
#pragma unroll
    for (int kc = 0; kc < 4; ++kc)
#pragma unroll
        for (int nt = 0; nt < 4; ++nt) {
            half8 b0 = *(const half8*)&fragL[((kc * 4 + nt) * 64 + lane) * 8];
            acc[nt] = __builtin_amdgcn_mfma_f32_16x16x32_f16(A_[kc], b0,
                                                             acc[nt], 0, 0, 0);
        }

    // ---- relu -> Hb (wave-local swizzled slice) ----
#pragma unroll
    for (int nt = 0; nt < 4; ++nt)
#pragma unroll
        for (int reg = 0; reg < 4; ++reg) {
            const int hr = m0 + qd * 4 + reg;
            const int nn = nt * 16 + n_;
            Hb[hr * 64 + (((nn >> 3) ^ (hr & 7)) * 8) + (nn & 7)] =
                (_Float16)fmaxf(acc[nt][reg], 0.f);
        }
    __builtin_amdgcn_s_waitcnt(0);   // drain LDS writes (wave-local dep)

    // ---- layer1: 8 MFMAs, B-frags from LDS ----
    const int row = m0 + n_;
    float4v acc1[4];
#pragma unroll
    for (int nt = 0; nt < 4; ++nt) {
        float4v t = {mb1v[nt], mb1v[nt], mb1v[nt], mb1v[nt]};
        acc1[nt] = t;
    }
#pragma unroll
    for (int kc = 0; kc < 2; ++kc) {
        half8 a1 = *(const half8*)&Hb[row * 64 + (((kc * 4 + qd) ^ (row & 7)) * 8)];
#pragma unroll
        for (int nt = 0; nt < 4; ++nt) {
            half8 b1 = *(const half8*)&fragL[((16 + kc * 4 + nt) * 64 + lane) * 8];
            acc1[nt] = __builtin_amdgcn_mfma_f32_16x16x32_f16(a1, b1,
                                                              acc1[nt], 0, 0, 0);
        }
    }

    // ---- layer2 + in-wave combine ----
    float p[4];
#pragma unroll
    for (int reg = 0; reg < 4; ++reg) {
        float s = 0.f;
#pragma unroll
        for (int nt = 0; nt < 4; ++nt)
            s = fmaf(fmaxf(acc1[nt][reg], 0.f), w2v[nt], s);
        s += __shfl_xor(s, 1, 64);
        s += __shfl_xor(s, 2, 64);
        s += __shfl_xor(s, 4, 64);
        s += __shfl_xor(s, 8, 64);
        p[reg] = s + mb2s;
    }

    float a0s = __shfl(area, qd * 4 + 0, 64);
    float a1s = __shfl(area, qd * 4 + 1, 64);
    float a2s = __shfl(area, qd * 4 + 2, 64);
    float a3s = __shfl(area, qd * 4 + 3, 64);
    int   oq  = __shfl(qq,   qd * 4, 64);

    if (n_ == 0) {
        float num = p[0] * a3s + p[1] * a2s + p[2] * a1s + p[3] * a0s;
        float den = a0s + a1s + a2s + a3s;
        out[oq] = num / den;
    }
}

// ---------------------------------------------------------------------------
extern "C" void kernel_launch(void* const* d_in, const int* in_sizes, int n_in,
                              void* d_out, int out_size, void* d_ws, size_t ws_size,
                              hipStream_t stream) {
    (void)in_sizes; (void)n_in; (void)out_size; (void)ws_size;
    const float* feats2  = (const float*)d_in[0];
    const float* feats4  = (const float*)d_in[1];
    const float* feats32 = (const float*)d_in[2];
    const float* coords  = (const float*)d_in[3];
    const float* cells   = (const float*)d_in[4];
    const float* w2  = (const float*)d_in[5];
    const float* b2  = (const float*)d_in[6];
    const float* w4  = (const float*)d_in[7];
    const float* b4  = (const float*)d_in[8];
    const float* w32 = (const float*)d_in[9];
    const float* b32 = (const float*)d_in[10];
    const float* wf  = (const float*)d_in[11];
    const float* bf  = (const float*)d_in[12];
    const float* mw0 = (const float*)d_in[13];
    const float* mb0 = (const float*)d_in[14];
    const float* mw1 = (const float*)d_in[15];
    const float* mb1 = (const float*)d_in[16];
    const float* mw2 = (const float*)d_in[17];
    const float* mb2 = (const float*)d_in[18];

    float* ws = (float*)d_ws;
    float*    a4s   = ws;                          // 589824 f
    float*    a32s  = a4s + 589824;                // 36864 f
    _Float16* xcatH = (_Float16*)(a32s + 36864);   // 7,077,888 h
    _Float16* asppH = xcatH + 7077888;             // 7,077,888 h
    _Float16* fragTab  = asppH + 7077888;          // 12,288 h
    _Float16* fragTabW = fragTab + 12288;          // 82,944 h
    float4v*  qdata = (float4v*)(fragTabW + 82944);   // NQ * 16 B
    int*      qidx  = (int*)(qdata + NQ);             // NQ ints
    int*      cntT  = qidx + NQ;                      // NFLAT ints
    int*      scanEx = cntT + NFLAT;                  // NFLAT ints
    int*      chunkTot = scanEx + NFLAT;              // 81 ints (pad 128)
    unsigned short* lrank = (unsigned short*)(chunkTot + 128);  // NQ u16
    float* out = (float*)d_out;

    fused_front<<<1029, 1024, 0, stream>>>(coords, cntT, lrank,
                                           mw0, mw1, wf, fragTab, fragTabW,
                                           feats4, w4, b4, feats32, w32, b32,
                                           a4s, a32s, feats2, w2, b2, xcatH);
    fused_mid<<<1233, 1024, 0, stream>>>(cntT, scanEx, chunkTot,
                                         a4s, a32s, xcatH);
    fused_back<<<1728, 256, 0, stream>>>(xcatH, fragTabW, bf, asppH,
                                         coords, cells, scanEx, chunkTot,
                                         lrank, qidx, qdata);
    decoder_mlp_mfma<<<18432, 256, 0, stream>>>(asppH, qidx, qdata, fragTab,
                                                mb0, mb1, mw2, mb2, out);
}